// Round 9
// baseline (645.813 us; speedup 1.0000x reference)
//
#include <hip/hip_runtime.h>
#include <hip/hip_bf16.h>
#include <math.h>

typedef __hip_bfloat16 bf16;
typedef __attribute__((ext_vector_type(8))) short short8;
typedef __attribute__((ext_vector_type(4))) short short4v;
typedef __attribute__((ext_vector_type(4))) float f32x4;

#define BT   4096   // B*T rows
#define DM   1024
#define NH   16
#define DH   64
#define TSEQ 2048

__device__ __forceinline__ float wave_sum(float v){
#pragma unroll
  for (int o = 32; o; o >>= 1) v += __shfl_xor(v, o);
  return v;
}

__device__ __forceinline__ float block_sum(float v){
  __shared__ float sm[4];
  v = wave_sum(v);
  __syncthreads();
  if ((threadIdx.x & 63) == 0) sm[threadIdx.x >> 6] = v;
  __syncthreads();
  return sm[0] + sm[1] + sm[2] + sm[3];
}

__device__ __forceinline__ float softplusf(float x){
  return x > 20.f ? x : __logf(1.f + __expf(x));   // fast: |err| ~1e-6, tol 0.03
}

__device__ __forceinline__ short f2bf(float f){
  unsigned u = __builtin_bit_cast(unsigned, f);
  u += 0x7FFF + ((u >> 16) & 1);          // RNE; inputs finite
  return (short)(u >> 16);
}

__device__ __forceinline__ short8 ld8(const short* p){  // two 8B LDS reads
  short4v a = *(const short4v*)p;
  short4v b = *(const short4v*)(p + 4);
  short8 r;
  r[0]=a[0]; r[1]=a[1]; r[2]=a[2]; r[3]=a[3];
  r[4]=b[0]; r[5]=b[1]; r[6]=b[2]; r[7]=b[3];
  return r;
}

__device__ __forceinline__ void async16(const short* g, short* l){
  __builtin_amdgcn_global_load_lds(
      (const __attribute__((address_space(1))) void*)g,
      (__attribute__((address_space(3))) void*)l, 16, 0, 0);
}

// Bijective XCD chunk swizzle (m204): XCD k (= lin%8 under round-robin dispatch)
// processes a contiguous range of logical workgroup ids -> L2-local panel reuse.
__device__ __forceinline__ int xcd_swizzle(int lin, int nwg){
  const int q = nwg >> 3, r = nwg & 7;
  const int xcd = lin & 7, i = lin >> 3;
  return (xcd < r ? xcd * (q + 1) : r * (q + 1) + (xcd - r) * q) + i;
}

// ---------------- weight convert+transpose: f32 [K][N] -> bf16 [N][K] ----------------
__device__ __forceinline__ void wt_body(const float* __restrict__ src,
    short* __restrict__ dst, int K, int N){
  __shared__ short T[32][33];
  const int tx = threadIdx.x & 31, ty = threadIdx.x >> 5;  // ty 0..7
  const int n0 = blockIdx.x << 5, k0 = blockIdx.y << 5;
#pragma unroll
  for (int r = 0; r < 4; r++){
    const int k = k0 + (ty << 2) + r;
    const int n = n0 + tx;
    T[tx][(ty << 2) + r] = (n < N) ? f2bf(src[(long)k * N + n]) : (short)0;
  }
  __syncthreads();
#pragma unroll
  for (int r = 0; r < 4; r++){
    const int n = n0 + (ty << 2) + r;
    if (n < N) dst[(long)n * K + k0 + tx] = T[(ty << 2) + r][tx];
  }
}

__global__ __launch_bounds__(256) void wt_kernel(const float* __restrict__ src,
    short* __restrict__ dst, int K, int N){
  wt_body(src, dst, K, N);
}

// six same-shape (1024x1024) weight transposes in one launch (z selects slot)
__global__ __launch_bounds__(256) void wt6_kernel(
    const float* s0, const float* s1, const float* s2, const float* s3,
    const float* s4, const float* s5,
    short* d0, short* d1, short* d2, short* d3, short* d4, short* d5){
  const float* src; short* dst;
  switch (blockIdx.z){
    case 0: src = s0; dst = d0; break;
    case 1: src = s1; dst = d1; break;
    case 2: src = s2; dst = d2; break;
    case 3: src = s3; dst = d3; break;
    case 4: src = s4; dst = d4; break;
    default: src = s5; dst = d5; break;
  }
  wt_body(src, dst, DM, DM);
}

// ------- bias concat fill: [0..3071]=0, gate_b, p_b, clock_b (5136 entries) -------
__global__ __launch_bounds__(256) void biascat_fill(const float* __restrict__ gb,
    const float* __restrict__ pb, const float* __restrict__ cb, float* __restrict__ out){
  const int i = blockIdx.x * 256 + threadIdx.x;
  if (i >= 5136) return;
  float v = 0.f;
  if (i >= 5120) v = cb[i - 5120];
  else if (i >= 4096) v = pb[i - 4096];
  else if (i >= 3072) v = gb[i - 3072];
  out[i] = v;
}

// ---------------- LayerNorm: one block per row of 1024, bf16 out ----------------
__global__ __launch_bounds__(256) void ln_kernel(const float* __restrict__ xin,
    const float* __restrict__ g, const float* __restrict__ bb, short* __restrict__ out){
  const long row = blockIdx.x;
  const int tid = threadIdx.x;
  float v[4];
#pragma unroll
  for (int i = 0; i < 4; i++) v[i] = xin[row * DM + tid + i * 256];
  float s = block_sum(v[0] + v[1] + v[2] + v[3]);
  const float mu = s * (1.f / DM);
  float d2 = 0.f;
#pragma unroll
  for (int i = 0; i < 4; i++){ float dd = v[i] - mu; d2 = fmaf(dd, dd, d2); }
  d2 = block_sum(d2);
  const float rstd = rsqrtf(d2 * (1.f / DM) + 1e-5f);
#pragma unroll
  for (int i = 0; i < 4; i++){
    int c = tid + i * 256;
    out[row * DM + c] = f2bf(fmaf((v[i] - mu) * rstd, g[c], bb[c]));
  }
}

// ---------------- MFMA GEMM (128x128 tile, 4 waves, wave-tile 64x64) ----------------
// Used for out-proj (EPI=4) and MLP2 (EPI=6, split-K=4) -- proven 93.8us config (R6).
// K-loop: depth-2 software pipeline (3 LDS buffers), counted vmcnt, 1 barrier/step.
// Grid: bijective XCD swizzle. LDS: 16B-chunk XOR swizzle -> conflicts = 0 (R4-proven).
template <int EPI>
__global__ __launch_bounds__(256) void gemm_bt(
    const short* __restrict__ A, const short* __restrict__ Bt,
    const float* __restrict__ bias, const float* __restrict__ resf,
    const float* __restrict__ bias2, float* __restrict__ Cf2,
    float* __restrict__ Cf, short* __restrict__ Cbf, int M, int N, int K)
{
  __shared__ __attribute__((aligned(16))) short As[3][4096];
  __shared__ __attribute__((aligned(16))) short Bs[3][4096];
  const int tid = threadIdx.x;
  const int lane = tid & 63, w = tid >> 6;
  const int l16 = lane & 15, quad = lane >> 4;
  const int wm = w >> 1, wn = w & 1;
  const int gx = (int)gridDim.x, gy = (int)gridDim.y;
  int wg = xcd_swizzle((int)blockIdx.x + gx * ((int)blockIdx.y + gy * (int)blockIdx.z),
                       gx * gy * (int)gridDim.z);
  const int bx = wg % gx; wg /= gx;
  const int by = wg % gy; wg /= gy;
  const int bz = wg;
  const int bm0 = by << 7, bn0 = bx << 7;
  const int ks = K / (int)gridDim.z;
  const int kbeg = bz * ks;
  const int nt = ks >> 5;                    // number of 32-wide K-steps

  const int csw = (tid >> 3) & 3;            // = (lds_row>>1)&3 for both chunks
  const int r0 = tid >> 2,        c0 = (tid & 3) ^ csw;
  const int r1 = 64 + (tid >> 2);            // second chunk row (same csw)
  const short* ga0 = A  + (long)(bm0 + r0) * K + kbeg + c0 * 8;
  const short* ga1 = A  + (long)(bm0 + r1) * K + kbeg + c0 * 8;
  const short* gb0 = Bt + (long)min(bn0 + r0, N - 1) * K + kbeg + c0 * 8;
  const short* gb1 = Bt + (long)min(bn0 + r1, N - 1) * K + kbeg + c0 * 8;
  const int wofs = w << 9;                   // per-wave LDS base (shorts)

#define STAGE(buf, t) do {                                   \
    const long ko_ = (long)(t) * 32;                         \
    async16(ga0 + ko_, &As[buf][wofs]);                      \
    async16(gb0 + ko_, &Bs[buf][wofs]);                      \
    async16(ga1 + ko_, &As[buf][2048 + wofs]);               \
    async16(gb1 + ko_, &Bs[buf][2048 + wofs]);               \
  } while (0)

  f32x4 acc[4][4] = {};

  STAGE(0, 0);
  if (nt > 1) STAGE(1, 1);

  const int qsw = (quad ^ ((l16 >> 1) & 3)) * 8;

  int cur = 0, stg = 2;
  for (int t = 0; t < nt; t++){
    if (t + 1 < nt){
      asm volatile("s_waitcnt vmcnt(4)" ::: "memory");   // tile t staged 2 phases ago
    } else {
      asm volatile("s_waitcnt vmcnt(0)" ::: "memory");   // last tile: drain
    }
    __builtin_amdgcn_s_barrier();
    __builtin_amdgcn_sched_barrier(0);       // pin: no ds_read/stage hoists above barrier
    if (t + 2 < nt) STAGE(stg, t + 2);       // buffer stg was last read at iter t-1
    short8 af[4], bfr[4];
#pragma unroll
    for (int i = 0; i < 4; i++){
      af[i]  = *(const short8*)&As[cur][(wm * 64 + i * 16 + l16) * 32 + qsw];
      bfr[i] = *(const short8*)&Bs[cur][(wn * 64 + i * 16 + l16) * 32 + qsw];
    }
#pragma unroll
    for (int i = 0; i < 4; i++)
#pragma unroll
      for (int j = 0; j < 4; j++)
        acc[i][j] = __builtin_amdgcn_mfma_f32_16x16x32_bf16(af[i], bfr[j], acc[i][j], 0, 0, 0);
    cur = (cur == 2) ? 0 : cur + 1;
    stg = (stg == 2) ? 0 : stg + 1;
  }
#undef STAGE

#pragma unroll
  for (int i = 0; i < 4; i++){
#pragma unroll
    for (int r = 0; r < 4; r++){
      const int row = bm0 + wm * 64 + i * 16 + quad * 4 + r;
#pragma unroll
      for (int j = 0; j < 4; j++){
        const int col = bn0 + wn * 64 + j * 16 + l16;
        if (col < N){
          float v = acc[i][j][r];
          const long off = (long)row * N + col;
          if constexpr (EPI >= 1 && EPI != 6) v += bias[col];
          if constexpr (EPI == 2 || EPI == 4) v += resf[off];
          if constexpr (EPI == 3){
            v = 0.5f * v * (1.f + erff(v * 0.70710678118654752f));
            Cbf[off] = f2bf(v);
          } else if constexpr (EPI == 4){
            Cf[off] = v;
            Cf2[off] = v + bias2[col];
          } else if constexpr (EPI == 6){
            unsafeAtomicAdd(&Cf[off], v);
          } else {
            Cf[off] = v;
          }
        }
      }
    }
  }
}

// ------- MFMA GEMM v4: 256^2/BK=64/8-wave geometry + TRUE T4 counted vmcnt -------
// Delta vs R8's bt3 (which drained vmcnt(0) per K-tile = the m218 "drain-0" null):
// stage runs TWO K-tiles ahead (16 loads in flight); per-tile wait is vmcnt(8) --
// waits only for the tile staged 2 tiles ago (~2 compute-tiles of slack >> 900cy
// HBM latency) and NEVER drains until the final tile. Invariant: <=16 outstanding,
// oldest 8 = the tile about to be read; per-wave wait BEFORE s_barrier makes it
// block-global (each wave covers its own 8 loads; FIFO retirement, m135).
// Buffer safety: barrier AFTER the MFMA cluster separates all waves' ds_reads of
// buf[cur] from re-staging tile t+2 into it.
// LDS 128KB (2 x 256x64 x A,B), 1 blk/CU. Same XOR swizzle algebra as bt3
// (refcheck'd R8, conflicts=0). setprio around MFMA (T5).
template <int EPI>
__global__ __launch_bounds__(512, 2) void gemm_bt4(
    const short* __restrict__ A, const short* __restrict__ Bt,
    const float* __restrict__ bias,
    float* __restrict__ Cf, short* __restrict__ Cbf, int M, int N, int K)
{
  __shared__ __attribute__((aligned(16))) short As[2][16384];   // 256 x 64
  __shared__ __attribute__((aligned(16))) short Bs[2][16384];   // 256 x 64
  const int tid = threadIdx.x;
  const int lane = tid & 63, w = tid >> 6;       // 8 waves
  const int l16 = lane & 15, quad = lane >> 4;
  const int wm = w >> 2, wn = w & 3;             // 2M x 4N, wave tile 128x64
  const int gx = (int)gridDim.x, gy = (int)gridDim.y;
  int wg = xcd_swizzle((int)blockIdx.x + gx * ((int)blockIdx.y + gy * (int)blockIdx.z),
                       gx * gy * (int)gridDim.z);
  const int bx = wg % gx; wg /= gx;
  const int by = wg % gy; wg /= gy;
  const int bz = wg;
  const int bm0 = by << 8, bn0 = bx << 8;        // 256x256 tiles
  const int ks = K / (int)gridDim.z;
  const int kbeg = bz * ks;
  const int nt = ks >> 6;                        // 64-wide K-steps

  // staging: tile 256 rows x 8 chunks(16B); slot lin = p*512 + tid ->
  // row = p*64 + (tid>>3), chunk slot = tid&7; source chunk pre-XOR'd (^ row&7).
  const int rr = tid >> 3;                       // 0..63
  const int csw = (tid & 7) ^ (rr & 7);
  const short* ga0 = A  + (long)(bm0 + rr)       * K + kbeg + csw * 8;
  const short* ga1 = A  + (long)(bm0 + 64 + rr)  * K + kbeg + csw * 8;
  const short* ga2 = A  + (long)(bm0 + 128 + rr) * K + kbeg + csw * 8;
  const short* ga3 = A  + (long)(bm0 + 192 + rr) * K + kbeg + csw * 8;
  const short* gb0 = Bt + (long)min(bn0 + rr, N - 1)       * K + kbeg + csw * 8;
  const short* gb1 = Bt + (long)min(bn0 + 64 + rr, N - 1)  * K + kbeg + csw * 8;
  const short* gb2 = Bt + (long)min(bn0 + 128 + rr, N - 1) * K + kbeg + csw * 8;
  const short* gb3 = Bt + (long)min(bn0 + 192 + rr, N - 1) * K + kbeg + csw * 8;
  const int wofs = w << 9;                       // per-wave LDS base (shorts)

#define STAGE4(buf, t) do {                                  \
    const long ko_ = (long)(t) * 64;                         \
    async16(ga0 + ko_, &As[buf][wofs]);                      \
    async16(ga1 + ko_, &As[buf][4096 + wofs]);               \
    async16(ga2 + ko_, &As[buf][8192 + wofs]);               \
    async16(ga3 + ko_, &As[buf][12288 + wofs]);              \
    async16(gb0 + ko_, &Bs[buf][wofs]);                      \
    async16(gb1 + ko_, &Bs[buf][4096 + wofs]);               \
    async16(gb2 + ko_, &Bs[buf][8192 + wofs]);               \
    async16(gb3 + ko_, &Bs[buf][12288 + wofs]);              \
  } while (0)

  f32x4 acc[8][4] = {};

  STAGE4(0, 0);
  if (nt > 1) STAGE4(1, 1);                  // 16 loads in flight

  int cur = 0;
  for (int t = 0; t < nt; t++){
    if (t + 1 < nt){
      asm volatile("s_waitcnt vmcnt(8)" ::: "memory");  // tile t landed; t+1 stays in flight
    } else {
      asm volatile("s_waitcnt vmcnt(0)" ::: "memory");  // final tile only
    }
    __builtin_amdgcn_s_barrier();            // per-wave wait + barrier = block-global
    __builtin_amdgcn_sched_barrier(0);
#pragma unroll
    for (int kh = 0; kh < 2; kh++){          // two 32-wide k-halves of BK=64
      const int ksw = (((kh << 2) + quad) ^ (l16 & 7)) * 8;
      short8 af[8], bfr[4];
#pragma unroll
      for (int i = 0; i < 8; i++)
        af[i] = *(const short8*)&As[cur][(wm * 128 + i * 16 + l16) * 64 + ksw];
#pragma unroll
      for (int j = 0; j < 4; j++)
        bfr[j] = *(const short8*)&Bs[cur][(wn * 64 + j * 16 + l16) * 64 + ksw];
      __builtin_amdgcn_s_setprio(1);
#pragma unroll
      for (int i = 0; i < 8; i++)
#pragma unroll
        for (int j = 0; j < 4; j++)
          acc[i][j] = __builtin_amdgcn_mfma_f32_16x16x32_bf16(af[i], bfr[j], acc[i][j], 0, 0, 0);
      __builtin_amdgcn_s_setprio(0);
    }
    __builtin_amdgcn_s_barrier();            // all waves done reading buf[cur]
    __builtin_amdgcn_sched_barrier(0);
    if (t + 2 < nt) STAGE4(cur, t + 2);      // overwrite freed buffer, 2 tiles ahead
    cur ^= 1;
  }
#undef STAGE4

#pragma unroll
  for (int i = 0; i < 8; i++){
#pragma unroll
    for (int r = 0; r < 4; r++){
      const int row = bm0 + wm * 128 + i * 16 + quad * 4 + r;
#pragma unroll
      for (int j = 0; j < 4; j++){
        const int col = bn0 + wn * 64 + j * 16 + l16;
        if (col < N){
          float v = acc[i][j][r];
          const long off = (long)row * N + col;
          if constexpr (EPI >= 1 && EPI != 6) v += bias[col];
          if constexpr (EPI == 3){
            v = 0.5f * v * (1.f + erff(v * 0.70710678118654752f));
            Cbf[off] = f2bf(v);
          } else if constexpr (EPI == 5){
            if (col < 5120)
              Cf[(long)(col >> 10) * 4194304 + (long)row * 1024 + (col & 1023)] = v;
            else
              Cf[20971520 + (long)row * 16 + (col - 5120)] = v;   // CLKr (slot 5)
          } else if constexpr (EPI == 6){
            unsafeAtomicAdd(&Cf[off], v);
          } else {
            Cf[off] = v;
          }
        }
      }
    }
  }
}

// ---------------- Chunked scans over T (32 chunks x 64) ----------------
// p1 also converts V f32 -> bf16 Vh (XNb overlay; XNb dead after proj GEMM)
__global__ __launch_bounds__(256) void scan_p1(float* __restrict__ G, const float* __restrict__ P,
    const float* __restrict__ Vf, short* __restrict__ Vh,
    float* __restrict__ cmax, float* __restrict__ gsum){
  const int tid = blockIdx.x * 256 + threadIdx.x;    // 65536
  const int d = tid & 63, c = (tid >> 6) & 31, bh = tid >> 11;
  const int h = bh & 15, b = bh >> 4;
  const long base = (((long)(b * TSEQ + c * 64)) * NH + h) * 64 + d;
  float mx = -1e30f, gs = 0.f;
  for (int tt = 0; tt < 64; tt++){
    const long idx = base + (long)tt * (NH * 64);
    float gj = -softplusf(G[idx]);
    G[idx] = gj;
    gs += gj;
    mx = fmaxf(mx, P[idx]);
    Vh[idx] = f2bf(Vf[idx]);
  }
  const int chain = bh * 64 + d;
  cmax[chain * 32 + c] = mx;
  gsum[chain * 32 + c] = gs;
}

__global__ void scan_p2(const float* __restrict__ cmax, const float* __restrict__ gsum,
                        float* __restrict__ pmax, float* __restrict__ gpre){
  const int chain = blockIdx.x * 256 + threadIdx.x;  // 2048
  float mx = -1e30f;
  for (int c = 0; c < 32; c++) mx = fmaxf(mx, cmax[chain * 32 + c]);
  pmax[chain] = mx;
  float run = 0.f;
  for (int c = 0; c < 32; c++){ gpre[chain * 32 + c] = run; run += gsum[chain * 32 + c]; }
}

// p3 also applies l2norm + RoPE to Q,K (wave lanes == the 64 d-values of one row)
// trig: exact sinf/cosf once per chunk, then incremental angle rotation (4 FMA/step;
// drift ~6e-5 over 63 steps, tol 0.03). expf -> __expf throughout.
__global__ __launch_bounds__(256) void scan_p3(const float* __restrict__ G, float* __restrict__ P,
    const float* __restrict__ CLKr, float* __restrict__ Q, float* __restrict__ K,
    const float* __restrict__ pmax, const float* __restrict__ gpre, float* __restrict__ psum){
  const int tid = blockIdx.x * 256 + threadIdx.x;
  const int d = tid & 63, c = (tid >> 6) & 31, bh = tid >> 11;
  const int h = bh & 15, b = bh >> 4;
  const int chain = bh * 64 + d;
  const long base = (((long)(b * TSEQ + c * 64)) * NH + h) * 64 + d;
  const float pm = pmax[chain];
  const float freq = expf(-(float)(d >> 1) * 0.28782313662425575f); // ln(1e4)/32
  // incremental rotation state: angle th = t*freq, t starts at c*64
  float sn = sinf((float)(c * 64) * freq);
  float cn = cosf((float)(c * 64) * freq);
  const float sf = sinf(freq), cf = cosf(freq);
  float grun = gpre[chain * 32 + c];
  float ps = 0.f;
  for (int tt = 0; tt < 64; tt++){
    const long idx = base + (long)tt * (NH * 64);
    const int t = c * 64 + tt;
    float clk = softplusf(CLKr[(long)(b * TSEQ + t) * NH + h]);
    float pe = __expf(P[idx] - pm) * clk;
    P[idx] = pe; ps += pe;
    grun += G[idx];
    float gc = __expf(fminf(fmaxf(grun, -60.f), 50.f));
    {
      float q = Q[idx];
      float n = sqrtf(wave_sum(q * q));
      q = q / fmaxf(n, 1e-12f);
      float pr = __shfl_xor(q, 1);
      q = (d & 1) ? fmaf(pr, sn, q * cn) : fmaf(q, cn, -pr * sn);
      Q[idx] = q * gc;
    }
    {
      float k = K[idx];
      float n = sqrtf(wave_sum(k * k));
      k = k / fmaxf(n, 1e-12f);
      float pr = __shfl_xor(k, 1);
      k = (d & 1) ? fmaf(pr, sn, k * cn) : fmaf(k, cn, -pr * sn);
      K[idx] = k / (gc + 1e-8f);
    }
    // rotate (sn,cn) by freq
    const float ns = fmaf(sn, cf, cn * sf);
    const float nc = fmaf(cn, cf, -sn * sf);
    sn = ns; cn = nc;
  }
  psum[chain * 32 + c] = ps;
}

__global__ void scan_p4(const float* __restrict__ psum, float* __restrict__ ppre){
  const int chain = blockIdx.x * 256 + threadIdx.x;
  float run = 0.f;
  for (int c = 0; c < 32; c++){ ppre[chain * 32 + c] = run; run += psum[chain * 32 + c]; }
}

// final scan: emits bf16 Qh (pre-scaled by 0.125) and bf16 Kh (V f32 dead by now)
__global__ __launch_bounds__(256) void scan_p5(const float* __restrict__ P, const float* __restrict__ Q,
    const float* __restrict__ K, const float* __restrict__ ppre,
    short* __restrict__ Qh, short* __restrict__ Kh){
  const int tid = blockIdx.x * 256 + threadIdx.x;
  const int d = tid & 63, c = (tid >> 6) & 31, bh = tid >> 11;
  const int h = bh & 15, b = bh >> 4;
  const int chain = bh * 64 + d;
  const long base = (((long)(b * TSEQ + c * 64)) * NH + h) * 64 + d;
  float cs = ppre[chain * 32 + c];
  for (int tt = 0; tt < 64; tt++){
    const long idx = base + (long)tt * (NH * 64);
    float pe = P[idx];
    cs += pe;
    Qh[idx] = f2bf(Q[idx] / (cs + 1e-8f) * 0.125f);
    Kh[idx] = f2bf(K[idx] * pe);
  }
}

// ------- MFMA flash attention: fixed-m softmax (|s|<=0.125 < 0.25), deferred l,
//         register prefetch of next K/V tile, 64-key tiles, bf16 in/out -------
__global__ __launch_bounds__(256) void fattn_kernel(const short* __restrict__ Qh,
    const short* __restrict__ Kh, const short* __restrict__ Vh, short* __restrict__ O){
  __shared__ __attribute__((aligned(16))) short Ks[64][72];   // [key][d]
  __shared__ __attribute__((aligned(16))) short Vt[64][68];   // [d][key]
  __shared__ __attribute__((aligned(16))) short Ps[4][16][72];
  const int tid  = threadIdx.x;
  const int lane = tid & 63, w = tid >> 6;
  const int quad = lane >> 4, l16 = lane & 15;
  // XCD swizzle: keep all q-tiles of a (b,h) group on one XCD (K/V L2 reuse);
  // chunk-local dispatch order preserves heavy-first (qt descending).
  const int gx = (int)gridDim.x;
  int wgs = xcd_swizzle((int)blockIdx.x + gx * (int)blockIdx.y, gx * (int)gridDim.y);
  const int bxs = wgs % gx;
  const int bh = wgs / gx, h = bh & 15, b = bh >> 4;
  const int qt = gx - 1 - bxs;                        // heavy blocks first
  const int q0  = qt << 6;
  const int qw0 = q0 + w * 16;
  const long strideT = NH * DH;
  const long base_bh = ((long)b * TSEQ * NH + h) * DH;

  const short* qp = Qh + base_bh + (long)(qw0 + l16) * strideT + quad * 8;
  const short8 qa0 = *(const short8*)qp;
  const short8 qa1 = *(const short8*)(qp + 32);

  f32x4 oacc[4] = {{0,0,0,0},{0,0,0,0},{0,0,0,0},{0,0,0,0}};
  float lpart[4] = {0.f,0.f,0.f,0.f};    // per-lane partial row sums (fixed m)

  const int krow = tid >> 2, kcol = (tid & 3) << 4;  // K staging: 64 rows x 64 shorts
  const int vkey = tid & 63, vd0 = (tid >> 6) << 4;  // V staging (transpose)
  const short* kbase = Kh + base_bh + (long)krow * strideT + kcol;
  const short* vbase = Vh + base_bh + (long)vkey * strideT + vd0;

  // prefetch tile 0 into registers
  short8 kr0 = *(const short8*)kbase;
  short8 kr1 = *(const short8*)(kbase + 8);
  short8 vr0 = *(const short8*)vbase;
  short8 vr1 = *(const short8*)(vbase + 8);

  const int ntiles = qt + 1;
  for (int t = 0; t < ntiles; t++){
    // commit prefetched tile to LDS
    *(short8*)&Ks[krow][kcol]     = kr0;
    *(short8*)&Ks[krow][kcol + 8] = kr1;
#pragma unroll
    for (int j = 0; j < 8; j++) Vt[vd0 + j][vkey] = vr0[j];
#pragma unroll
    for (int j = 0; j < 8; j++) Vt[vd0 + 8 + j][vkey] = vr1[j];
    __syncthreads();
    // issue next tile's loads (overlap with compute)
    if (t + 1 < ntiles){
      const long off = (long)(t + 1) * (64 * strideT);
      kr0 = *(const short8*)(kbase + off);
      kr1 = *(const short8*)(kbase + off + 8);
      vr0 = *(const short8*)(vbase + off);
      vr1 = *(const short8*)(vbase + off + 8);
    }
    const int kt0 = t << 6;
    // ---- S = Q K^T ----
    f32x4 c[4] = {{0,0,0,0},{0,0,0,0},{0,0,0,0},{0,0,0,0}};
#pragma unroll
    for (int kg = 0; kg < 4; kg++){
      const short8 b0 = ld8(&Ks[kg * 16 + l16][quad * 8]);
      const short8 b1 = ld8(&Ks[kg * 16 + l16][32 + quad * 8]);
      c[kg] = __builtin_amdgcn_mfma_f32_16x16x32_bf16(qa0, b0, c[kg], 0, 0, 0);
      c[kg] = __builtin_amdgcn_mfma_f32_16x16x32_bf16(qa1, b1, c[kg], 0, 0, 0);
    }
    // ---- causal mask (diagonal tiles only) ----
    if (kt0 + 63 > qw0){
#pragma unroll
      for (int kg = 0; kg < 4; kg++)
#pragma unroll
        for (int r = 0; r < 4; r++){
          const int qq = qw0 + quad * 4 + r;
          if (kt0 + kg * 16 + l16 > qq) c[kg][r] = -1e30f;
        }
    }
    // ---- fixed-m softmax: p = exp(s - 0.25); accumulate per-lane l partials ----
#pragma unroll
    for (int kg = 0; kg < 4; kg++)
#pragma unroll
      for (int r = 0; r < 4; r++) c[kg][r] = __expf(c[kg][r] - 0.25f);
#pragma unroll
    for (int r = 0; r < 4; r++)
      lpart[r] += (c[0][r] + c[1][r]) + (c[2][r] + c[3][r]);
    // ---- P -> LDS (C-layout) -> A-frags (same-wave round trip, no barrier) ----
#pragma unroll
    for (int kg = 0; kg < 4; kg++)
#pragma unroll
      for (int r = 0; r < 4; r++)
        Ps[w][quad * 4 + r][kg * 16 + l16] = f2bf(c[kg][r]);
    const short8 pa0 = ld8(&Ps[w][l16][quad * 8]);
    const short8 pa1 = ld8(&Ps[w][l16][32 + quad * 8]);
    // ---- O += P V ----
#pragma unroll
    for (int f = 0; f < 4; f++){
      const short8 vb0 = ld8(&Vt[f * 16 + l16][quad * 8]);
      const short8 vb1 = ld8(&Vt[f * 16 + l16][32 + quad * 8]);
      oacc[f] = __builtin_amdgcn_mfma_f32_16x16x32_bf16(pa0, vb0, oacc[f], 0, 0, 0);
      oacc[f] = __builtin_amdgcn_mfma_f32_16x16x32_bf16(pa1, vb1, oacc[f], 0, 0, 0);
    }
    __syncthreads();
  }
  // ---- epilogue: reduce l partials across the 16 col-lanes, scale, store ----
#pragma unroll
  for (int r = 0; r < 4; r++){
    float l = lpart[r];
#pragma unroll
    for (int o = 1; o <= 8; o <<= 1) l += __shfl_xor(l, o);
    const float inv = 1.f / l;
    const long row = base_bh + (long)(qw0 + quad * 4 + r) * strideT + l16;
#pragma unroll
    for (int f = 0; f < 4; f++) O[row + f * 16] = f2bf(oacc[f][r] * inv);
  }
}

extern "C" void kernel_launch(void* const* d_in, const int* in_sizes, int n_in,
                              void* d_out, int out_size, void* d_ws, size_t ws_size,
                              hipStream_t stream){
  const float* x       = (const float*)d_in[0];
  const float* Wq      = (const float*)d_in[1];
  const float* Wk      = (const float*)d_in[2];
  const float* Wv      = (const float*)d_in[3];
  const float* gate_w  = (const float*)d_in[4];
  const float* gate_b  = (const float*)d_in[5];
  const float* p_w     = (const float*)d_in[6];
  const float* p_b     = (const float*)d_in[7];
  const float* out_w   = (const float*)d_in[8];
  const float* out_b   = (const float*)d_in[9];
  const float* clock_w = (const float*)d_in[10];
  const float* clock_b = (const float*)d_in[11];
  const float* ln1_g   = (const float*)d_in[12];
  const float* ln1_b   = (const float*)d_in[13];
  const float* ln2_g   = (const float*)d_in[14];
  const float* ln2_b   = (const float*)d_in[15];
  const float* mlp_w1  = (const float*)d_in[16];
  const float* mlp_b1  = (const float*)d_in[17];
  const float* mlp_w2  = (const float*)d_in[18];
  const float* mlp_b2  = (const float*)d_in[19];
  float* outp = (float*)d_out;

  // ---- workspace layout (round-8-proven liveness) ----
  float* ws   = (float*)d_ws;
  float* C5   = ws;                     // slots 0..4 f32: Qb,Kb,Vf,Gb,Pb
  float* Qb   = ws;
  float* Kb   = ws + 4194304;
  float* Vf   = ws + 8388608;
  float* Gb   = ws + 12582912;
  float* Pb   = ws + 16777216;          // later X1
  float* CLKr = ws + 20971520;          // slot 5 (row*16 layout)
  float* cmax = CLKr + 65536;
  float* gsum = cmax + 65536;           // psum
  float* gpre = gsum + 65536;           // ppre
  float* pmax = gpre + 65536;
  float* biascat = cmax;                // disjoint lifetime with cmax
  short* sb   = (short*)(ws + 21235712);
  short* XNb  = sb;                     // 4M shorts (LN1 out); Vh overlay after proj
  short* Vh   = sb;                     //   written by scan_p1 (XNb dead by then)
  short* WcT  = sb + 4194304;           // concat [5136][1024] bf16 (q,k,v,gate,p,clock)
  short* OwT  = WcT + 5260288;          // 1M
  short* W1T  = OwT + 1048576;          // 4M [4096][1024]
  short* W2T  = W1T + 4194304;          // 4M [1024][4096]
  // overlays of the V f32 slot [8388608, 12582912) — written in scan_p5, V f32 dead:
  short* Qh  = (short*)(ws + 8388608);            // 8MB
  short* Kh  = (short*)(ws + 8388608 + 2097152);  // 8MB
  // other overlays:
  short* MID = (short*)ws;                        // 16M shorts over Qb+Kb
  short* Ob  = (short*)(ws + 12582912);           // over dead Gb (first 8MB)
  short* Hb  = (short*)(ws + 12582912 + 2097152); // over dead Gb (second 8MB)
  float* X1  = Pb;

  // ---- weight convert+transpose (bf16, [N][K]) ----
  wt6_kernel<<<dim3(32, 32, 6), 256, 0, stream>>>(
      Wq, Wk, Wv, gate_w, p_w, out_w,
      WcT, WcT + 1048576, WcT + 2097152, WcT + 3145728, WcT + 4194304, OwT);
  wt_kernel<<<dim3(1, 32), 256, 0, stream>>>(clock_w, WcT + 5242880, DM, NH);
  wt_kernel<<<dim3(128, 32), 256, 0, stream>>>(mlp_w1, W1T, DM, 4 * DM);
  wt_kernel<<<dim3(32, 128), 256, 0, stream>>>(mlp_w2, W2T, 4 * DM, DM);
  biascat_fill<<<21, 256, 0, stream>>>(gate_b, p_b, clock_b, biascat);

  ln_kernel<<<BT, 256, 0, stream>>>(x, ln1_g, ln1_b, XNb);

  // fused Q/K/V/gate/p/clock projection: N = 5136, scatter epilogue (bt4, counted vmcnt)
  gemm_bt4<5><<<dim3(21, BT / 256), 512, 0, stream>>>(
      XNb, WcT, biascat, C5, nullptr, BT, 5136, DM);

  scan_p1<<<256, 256, 0, stream>>>(Gb, Pb, Vf, Vh, cmax, gsum);
  scan_p2<<<8, 256, 0, stream>>>(cmax, gsum, pmax, gpre);
  scan_p3<<<256, 256, 0, stream>>>(Gb, Pb, CLKr, Qb, Kb, pmax, gpre, gsum);
  scan_p4<<<8, 256, 0, stream>>>(gsum, gpre);
  scan_p5<<<256, 256, 0, stream>>>(Pb, Qb, Kb, gpre, Qh, Kh);

  fattn_kernel<<<dim3(TSEQ / 64, 2 * NH), 256, 0, stream>>>(Qh, Kh, Vh, Ob);

  // out-proj: X1 = attn@out_w + out_b + x, fused init outp = X1 + mlp_b2 (128^2 tiles)
  gemm_bt<4><<<dim3(DM / 128, BT / 128), 256, 0, stream>>>(
      Ob, OwT, out_b, x, mlp_b2, outp, X1, nullptr, BT, DM, DM);
  ln_kernel<<<BT, 256, 0, stream>>>(X1, ln2_g, ln2_b, Hb);
  // MLP1: bt4 (counted vmcnt)
  gemm_bt4<3><<<dim3(4 * DM / 256, BT / 256), 512, 0, stream>>>(
      Hb, W1T, mlp_b1, nullptr, MID, BT, 4 * DM, DM);
  // MLP2: revert to proven 128^2 split-K=4 (R6: 93.8us; 256^2 tiles regressed it)
  gemm_bt<6><<<dim3(DM / 128, BT / 128, 4), 256, 0, stream>>>(
      MID, W2T, nullptr, nullptr, nullptr, nullptr, outp, nullptr, BT, DM, 4 * DM);
}

// Round 10
// 604.049 us; speedup vs baseline: 1.0691x; 1.0691x over previous
//
#include <hip/hip_runtime.h>
#include <hip/hip_bf16.h>
#include <math.h>

typedef __hip_bfloat16 bf16;
typedef __attribute__((ext_vector_type(8))) short short8;
typedef __attribute__((ext_vector_type(4))) short short4v;
typedef __attribute__((ext_vector_type(4))) float f32x4;

#define BT   4096   // B*T rows
#define DM   1024
#define NH   16
#define DH   64
#define TSEQ 2048

__device__ __forceinline__ float wave_sum(float v){
#pragma unroll
  for (int o = 32; o; o >>= 1) v += __shfl_xor(v, o);
  return v;
}

__device__ __forceinline__ float block_sum(float v){
  __shared__ float sm[4];
  v = wave_sum(v);
  __syncthreads();
  if ((threadIdx.x & 63) == 0) sm[threadIdx.x >> 6] = v;
  __syncthreads();
  return sm[0] + sm[1] + sm[2] + sm[3];
}

__device__ __forceinline__ float softplusf(float x){
  return x > 20.f ? x : __logf(1.f + __expf(x));   // fast: |err| ~1e-6, tol 0.03
}

__device__ __forceinline__ short f2bf(float f){
  unsigned u = __builtin_bit_cast(unsigned, f);
  u += 0x7FFF + ((u >> 16) & 1);          // RNE; inputs finite
  return (short)(u >> 16);
}

__device__ __forceinline__ short8 ld8(const short* p){  // two 8B LDS reads
  short4v a = *(const short4v*)p;
  short4v b = *(const short4v*)(p + 4);
  short8 r;
  r[0]=a[0]; r[1]=a[1]; r[2]=a[2]; r[3]=a[3];
  r[4]=b[0]; r[5]=b[1]; r[6]=b[2]; r[7]=b[3];
  return r;
}

__device__ __forceinline__ void async16(const short* g, short* l){
  __builtin_amdgcn_global_load_lds(
      (const __attribute__((address_space(1))) void*)g,
      (__attribute__((address_space(3))) void*)l, 16, 0, 0);
}

// Bijective XCD chunk swizzle (m204): XCD k (= lin%8 under round-robin dispatch)
// processes a contiguous range of logical workgroup ids -> L2-local panel reuse.
__device__ __forceinline__ int xcd_swizzle(int lin, int nwg){
  const int q = nwg >> 3, r = nwg & 7;
  const int xcd = lin & 7, i = lin >> 3;
  return (xcd < r ? xcd * (q + 1) : r * (q + 1) + (xcd - r) * q) + i;
}

// ---------------- weight convert+transpose: f32 [K][N] -> bf16 [N][K] ----------------
__device__ __forceinline__ void wt_body(const float* __restrict__ src,
    short* __restrict__ dst, int K, int N){
  __shared__ short T[32][33];
  const int tx = threadIdx.x & 31, ty = threadIdx.x >> 5;  // ty 0..7
  const int n0 = blockIdx.x << 5, k0 = blockIdx.y << 5;
#pragma unroll
  for (int r = 0; r < 4; r++){
    const int k = k0 + (ty << 2) + r;
    const int n = n0 + tx;
    T[tx][(ty << 2) + r] = (n < N) ? f2bf(src[(long)k * N + n]) : (short)0;
  }
  __syncthreads();
#pragma unroll
  for (int r = 0; r < 4; r++){
    const int n = n0 + (ty << 2) + r;
    if (n < N) dst[(long)n * K + k0 + tx] = T[(ty << 2) + r][tx];
  }
}

__global__ __launch_bounds__(256) void wt_kernel(const float* __restrict__ src,
    short* __restrict__ dst, int K, int N){
  wt_body(src, dst, K, N);
}

// six same-shape (1024x1024) weight transposes in one launch (z selects slot)
__global__ __launch_bounds__(256) void wt6_kernel(
    const float* s0, const float* s1, const float* s2, const float* s3,
    const float* s4, const float* s5,
    short* d0, short* d1, short* d2, short* d3, short* d4, short* d5){
  const float* src; short* dst;
  switch (blockIdx.z){
    case 0: src = s0; dst = d0; break;
    case 1: src = s1; dst = d1; break;
    case 2: src = s2; dst = d2; break;
    case 3: src = s3; dst = d3; break;
    case 4: src = s4; dst = d4; break;
    default: src = s5; dst = d5; break;
  }
  wt_body(src, dst, DM, DM);
}

// ------- bias concat fill: [0..3071]=0, gate_b, p_b, clock_b (5136 entries) -------
__global__ __launch_bounds__(256) void biascat_fill(const float* __restrict__ gb,
    const float* __restrict__ pb, const float* __restrict__ cb, float* __restrict__ out){
  const int i = blockIdx.x * 256 + threadIdx.x;
  if (i >= 5136) return;
  float v = 0.f;
  if (i >= 5120) v = cb[i - 5120];
  else if (i >= 4096) v = pb[i - 4096];
  else if (i >= 3072) v = gb[i - 3072];
  out[i] = v;
}

// ---------------- LayerNorm: one block per row of 1024, bf16 out ----------------
__global__ __launch_bounds__(256) void ln_kernel(const float* __restrict__ xin,
    const float* __restrict__ g, const float* __restrict__ bb, short* __restrict__ out){
  const long row = blockIdx.x;
  const int tid = threadIdx.x;
  float v[4];
#pragma unroll
  for (int i = 0; i < 4; i++) v[i] = xin[row * DM + tid + i * 256];
  float s = block_sum(v[0] + v[1] + v[2] + v[3]);
  const float mu = s * (1.f / DM);
  float d2 = 0.f;
#pragma unroll
  for (int i = 0; i < 4; i++){ float dd = v[i] - mu; d2 = fmaf(dd, dd, d2); }
  d2 = block_sum(d2);
  const float rstd = rsqrtf(d2 * (1.f / DM) + 1e-5f);
#pragma unroll
  for (int i = 0; i < 4; i++){
    int c = tid + i * 256;
    out[row * DM + c] = f2bf(fmaf((v[i] - mu) * rstd, g[c], bb[c]));
  }
}

// ---------------- MFMA GEMM: C[M,N] = A[M,K](bf16) @ Bt[N,K]^T(bf16) + epilogue ------
// R6-proven config (636us pipeline): 128x128 tile, 4 waves, wave-tile 64x64.
// EPI: 0 Cf=v | 1 Cf=v+bias | 2 Cf=v+bias+resf | 3 Cbf=bf16(gelu(v+bias))
//      4 Cf=v+bias+resf AND Cf2=Cf+bias2 | 5 proj-scatter (N=5136)
//      6 split-K partial: atomicAdd into Cf (pre-initialized)
// K-loop: depth-2 software pipeline (3 LDS buffers), counted vmcnt, 1 barrier/step.
// Grid: bijective XCD swizzle. LDS: 16B-chunk XOR swizzle -> conflicts = 0 (R4-proven).
template <int EPI>
__global__ __launch_bounds__(256) void gemm_bt(
    const short* __restrict__ A, const short* __restrict__ Bt,
    const float* __restrict__ bias, const float* __restrict__ resf,
    const float* __restrict__ bias2, float* __restrict__ Cf2,
    float* __restrict__ Cf, short* __restrict__ Cbf, int M, int N, int K)
{
  __shared__ __attribute__((aligned(16))) short As[3][4096];
  __shared__ __attribute__((aligned(16))) short Bs[3][4096];
  const int tid = threadIdx.x;
  const int lane = tid & 63, w = tid >> 6;
  const int l16 = lane & 15, quad = lane >> 4;
  const int wm = w >> 1, wn = w & 1;
  const int gx = (int)gridDim.x, gy = (int)gridDim.y;
  int wg = xcd_swizzle((int)blockIdx.x + gx * ((int)blockIdx.y + gy * (int)blockIdx.z),
                       gx * gy * (int)gridDim.z);
  const int bx = wg % gx; wg /= gx;
  const int by = wg % gy; wg /= gy;
  const int bz = wg;
  const int bm0 = by << 7, bn0 = bx << 7;
  const int ks = K / (int)gridDim.z;
  const int kbeg = bz * ks;
  const int nt = ks >> 5;                    // number of 32-wide K-steps

  const int csw = (tid >> 3) & 3;            // = (lds_row>>1)&3 for both chunks
  const int r0 = tid >> 2,        c0 = (tid & 3) ^ csw;
  const int r1 = 64 + (tid >> 2);            // second chunk row (same csw)
  const short* ga0 = A  + (long)(bm0 + r0) * K + kbeg + c0 * 8;
  const short* ga1 = A  + (long)(bm0 + r1) * K + kbeg + c0 * 8;
  const short* gb0 = Bt + (long)min(bn0 + r0, N - 1) * K + kbeg + c0 * 8;
  const short* gb1 = Bt + (long)min(bn0 + r1, N - 1) * K + kbeg + c0 * 8;
  const int wofs = w << 9;                   // per-wave LDS base (shorts)

#define STAGE(buf, t) do {                                   \
    const long ko_ = (long)(t) * 32;                         \
    async16(ga0 + ko_, &As[buf][wofs]);                      \
    async16(gb0 + ko_, &Bs[buf][wofs]);                      \
    async16(ga1 + ko_, &As[buf][2048 + wofs]);               \
    async16(gb1 + ko_, &Bs[buf][2048 + wofs]);               \
  } while (0)

  f32x4 acc[4][4] = {};

  STAGE(0, 0);
  if (nt > 1) STAGE(1, 1);

  const int qsw = (quad ^ ((l16 >> 1) & 3)) * 8;

  int cur = 0, stg = 2;
  for (int t = 0; t < nt; t++){
    if (t + 1 < nt){
      asm volatile("s_waitcnt vmcnt(4)" ::: "memory");   // tile t staged 2 phases ago
    } else {
      asm volatile("s_waitcnt vmcnt(0)" ::: "memory");   // last tile: drain
    }
    __builtin_amdgcn_s_barrier();
    __builtin_amdgcn_sched_barrier(0);       // pin: no ds_read/stage hoists above barrier
    if (t + 2 < nt) STAGE(stg, t + 2);       // buffer stg was last read at iter t-1
    short8 af[4], bfr[4];
#pragma unroll
    for (int i = 0; i < 4; i++){
      af[i]  = *(const short8*)&As[cur][(wm * 64 + i * 16 + l16) * 32 + qsw];
      bfr[i] = *(const short8*)&Bs[cur][(wn * 64 + i * 16 + l16) * 32 + qsw];
    }
#pragma unroll
    for (int i = 0; i < 4; i++)
#pragma unroll
      for (int j = 0; j < 4; j++)
        acc[i][j] = __builtin_amdgcn_mfma_f32_16x16x32_bf16(af[i], bfr[j], acc[i][j], 0, 0, 0);
    cur = (cur == 2) ? 0 : cur + 1;
    stg = (stg == 2) ? 0 : stg + 1;
  }
#undef STAGE

#pragma unroll
  for (int i = 0; i < 4; i++){
#pragma unroll
    for (int r = 0; r < 4; r++){
      const int row = bm0 + wm * 64 + i * 16 + quad * 4 + r;
#pragma unroll
      for (int j = 0; j < 4; j++){
        const int col = bn0 + wn * 64 + j * 16 + l16;
        if (col < N){
          float v = acc[i][j][r];
          const long off = (long)row * N + col;
          if constexpr (EPI >= 1 && EPI != 6) v += bias[col];
          if constexpr (EPI == 2 || EPI == 4) v += resf[off];
          if constexpr (EPI == 3){
            v = 0.5f * v * (1.f + erff(v * 0.70710678118654752f));
            Cbf[off] = f2bf(v);
          } else if constexpr (EPI == 4){
            Cf[off] = v;
            Cf2[off] = v + bias2[col];
          } else if constexpr (EPI == 5){
            if (col < 5120)
              Cf[(long)(col >> 10) * 4194304 + (long)row * 1024 + (col & 1023)] = v;
            else
              Cf[20971520 + (long)row * 16 + (col - 5120)] = v;   // CLKr (slot 5)
          } else if constexpr (EPI == 6){
            unsafeAtomicAdd(&Cf[off], v);     // global_atomic_add_f32, device scope
          } else {
            Cf[off] = v;
          }
        }
      }
    }
  }
}

// ---------------- Chunked scans over T (32 chunks x 64) ----------------
// p1 also converts V f32 -> bf16 Vh (XNb overlay; XNb dead after proj GEMM)
__global__ __launch_bounds__(256) void scan_p1(float* __restrict__ G, const float* __restrict__ P,
    const float* __restrict__ Vf, short* __restrict__ Vh,
    float* __restrict__ cmax, float* __restrict__ gsum){
  const int tid = blockIdx.x * 256 + threadIdx.x;    // 65536
  const int d = tid & 63, c = (tid >> 6) & 31, bh = tid >> 11;
  const int h = bh & 15, b = bh >> 4;
  const long base = (((long)(b * TSEQ + c * 64)) * NH + h) * 64 + d;
  float mx = -1e30f, gs = 0.f;
  for (int tt = 0; tt < 64; tt++){
    const long idx = base + (long)tt * (NH * 64);
    float gj = -softplusf(G[idx]);
    G[idx] = gj;
    gs += gj;
    mx = fmaxf(mx, P[idx]);
    Vh[idx] = f2bf(Vf[idx]);
  }
  const int chain = bh * 64 + d;
  cmax[chain * 32 + c] = mx;
  gsum[chain * 32 + c] = gs;
}

__global__ void scan_p2(const float* __restrict__ cmax, const float* __restrict__ gsum,
                        float* __restrict__ pmax, float* __restrict__ gpre){
  const int chain = blockIdx.x * 256 + threadIdx.x;  // 2048
  float mx = -1e30f;
  for (int c = 0; c < 32; c++) mx = fmaxf(mx, cmax[chain * 32 + c]);
  pmax[chain] = mx;
  float run = 0.f;
  for (int c = 0; c < 32; c++){ gpre[chain * 32 + c] = run; run += gsum[chain * 32 + c]; }
}

// p3 also applies l2norm + RoPE to Q,K (wave lanes == the 64 d-values of one row)
// trig: exact sinf/cosf once per chunk, then incremental angle rotation (4 FMA/step;
// drift ~6e-5 over 63 steps, tol 0.03). expf -> __expf throughout.
__global__ __launch_bounds__(256) void scan_p3(const float* __restrict__ G, float* __restrict__ P,
    const float* __restrict__ CLKr, float* __restrict__ Q, float* __restrict__ K,
    const float* __restrict__ pmax, const float* __restrict__ gpre, float* __restrict__ psum){
  const int tid = blockIdx.x * 256 + threadIdx.x;
  const int d = tid & 63, c = (tid >> 6) & 31, bh = tid >> 11;
  const int h = bh & 15, b = bh >> 4;
  const int chain = bh * 64 + d;
  const long base = (((long)(b * TSEQ + c * 64)) * NH + h) * 64 + d;
  const float pm = pmax[chain];
  const float freq = expf(-(float)(d >> 1) * 0.28782313662425575f); // ln(1e4)/32
  // incremental rotation state: angle th = t*freq, t starts at c*64
  float sn = sinf((float)(c * 64) * freq);
  float cn = cosf((float)(c * 64) * freq);
  const float sf = sinf(freq), cf = cosf(freq);
  float grun = gpre[chain * 32 + c];
  float ps = 0.f;
  for (int tt = 0; tt < 64; tt++){
    const long idx = base + (long)tt * (NH * 64);
    const int t = c * 64 + tt;
    float clk = softplusf(CLKr[(long)(b * TSEQ + t) * NH + h]);
    float pe = __expf(P[idx] - pm) * clk;
    P[idx] = pe; ps += pe;
    grun += G[idx];
    float gc = __expf(fminf(fmaxf(grun, -60.f), 50.f));
    {
      float q = Q[idx];
      float n = sqrtf(wave_sum(q * q));
      q = q / fmaxf(n, 1e-12f);
      float pr = __shfl_xor(q, 1);
      q = (d & 1) ? fmaf(pr, sn, q * cn) : fmaf(q, cn, -pr * sn);
      Q[idx] = q * gc;
    }
    {
      float k = K[idx];
      float n = sqrtf(wave_sum(k * k));
      k = k / fmaxf(n, 1e-12f);
      float pr = __shfl_xor(k, 1);
      k = (d & 1) ? fmaf(pr, sn, k * cn) : fmaf(k, cn, -pr * sn);
      K[idx] = k / (gc + 1e-8f);
    }
    // rotate (sn,cn) by freq
    const float ns = fmaf(sn, cf, cn * sf);
    const float nc = fmaf(cn, cf, -sn * sf);
    sn = ns; cn = nc;
  }
  psum[chain * 32 + c] = ps;
}

__global__ void scan_p4(const float* __restrict__ psum, float* __restrict__ ppre){
  const int chain = blockIdx.x * 256 + threadIdx.x;
  float run = 0.f;
  for (int c = 0; c < 32; c++){ ppre[chain * 32 + c] = run; run += psum[chain * 32 + c]; }
}

// final scan: emits bf16 Qh (pre-scaled by 0.125) and bf16 Kh (V f32 dead by now)
__global__ __launch_bounds__(256) void scan_p5(const float* __restrict__ P, const float* __restrict__ Q,
    const float* __restrict__ K, const float* __restrict__ ppre,
    short* __restrict__ Qh, short* __restrict__ Kh){
  const int tid = blockIdx.x * 256 + threadIdx.x;
  const int d = tid & 63, c = (tid >> 6) & 31, bh = tid >> 11;
  const int h = bh & 15, b = bh >> 4;
  const int chain = bh * 64 + d;
  const long base = (((long)(b * TSEQ + c * 64)) * NH + h) * 64 + d;
  float cs = ppre[chain * 32 + c];
  for (int tt = 0; tt < 64; tt++){
    const long idx = base + (long)tt * (NH * 64);
    float pe = P[idx];
    cs += pe;
    Qh[idx] = f2bf(Q[idx] / (cs + 1e-8f) * 0.125f);
    Kh[idx] = f2bf(K[idx] * pe);
  }
}

// ------- MFMA flash attention v2: 128-row Q blocks, 8 waves sharing one K/V staging.
// Tile-iterations halve vs the 64-row version (Sum(2qt+2)=272 vs Sum(qt+1)=528 per bh):
// half the staging stores, barriers, and prefetch loads; per-wave MFMA work unchanged.
// Fixed-m softmax (|s|<=0.125 < 0.25), deferred l, register prefetch, bf16 in/out. -------
__global__ __launch_bounds__(512, 2) void fattn_kernel(const short* __restrict__ Qh,
    const short* __restrict__ Kh, const short* __restrict__ Vh, short* __restrict__ O){
  __shared__ __attribute__((aligned(16))) short Ks[64][72];   // [key][d]
  __shared__ __attribute__((aligned(16))) short Vt[64][68];   // [d][key]
  __shared__ __attribute__((aligned(16))) short Ps[8][16][72];
  const int tid  = threadIdx.x;
  const int lane = tid & 63, w = tid >> 6;            // 8 waves x 16 q-rows
  const int quad = lane >> 4, l16 = lane & 15;
  // XCD swizzle keeps a (b,h)'s q-tiles on one XCD (K/V L2 reuse).
  const int gx = (int)gridDim.x;                      // 16
  int wgs = xcd_swizzle((int)blockIdx.x + gx * (int)blockIdx.y, gx * (int)gridDim.y);
  const int bxs = wgs % gx;
  const int bh = wgs / gx, h = bh & 15, b = bh >> 4;
  // qt order alternates by (bh>>1) parity: co-resident CU block pairs sum ~const work.
  const int qt = ((bh >> 1) & 1) ? bxs : (gx - 1 - bxs);
  const int q0  = qt << 7;
  const int qw0 = q0 + w * 16;
  const long strideT = NH * DH;
  const long base_bh = ((long)b * TSEQ * NH + h) * DH;

  const short* qp = Qh + base_bh + (long)(qw0 + l16) * strideT + quad * 8;
  const short8 qa0 = *(const short8*)qp;
  const short8 qa1 = *(const short8*)(qp + 32);

  f32x4 oacc[4] = {{0,0,0,0},{0,0,0,0},{0,0,0,0},{0,0,0,0}};
  float lpart[4] = {0.f,0.f,0.f,0.f};    // per-lane partial row sums (fixed m)

  // staging split across 512 threads: K 64x64 shorts (1 short8/thread),
  // V transpose 8 d-values/thread (w = d-group).
  const int krow = tid >> 3, kcol = (tid & 7) << 3;
  const int vkey = tid & 63, vd0 = w << 3;
  const short* kbase = Kh + base_bh + (long)krow * strideT + kcol;
  const short* vbase = Vh + base_bh + (long)vkey * strideT + vd0;

  // prefetch tile 0 into registers
  short8 kr0 = *(const short8*)kbase;
  short8 vr0 = *(const short8*)vbase;

  const int ntiles = 2 * qt + 2;          // keys 0 .. q0+127 covered
  for (int t = 0; t < ntiles; t++){
    // commit prefetched tile to LDS
    *(short8*)&Ks[krow][kcol] = kr0;
#pragma unroll
    for (int j = 0; j < 8; j++) Vt[vd0 + j][vkey] = vr0[j];
    __syncthreads();
    // issue next tile's loads (overlap with compute)
    if (t + 1 < ntiles){
      const long off = (long)(t + 1) * (64 * strideT);
      kr0 = *(const short8*)(kbase + off);
      vr0 = *(const short8*)(vbase + off);
    }
    const int kt0 = t << 6;
    // ---- S = Q K^T ----
    f32x4 c[4] = {{0,0,0,0},{0,0,0,0},{0,0,0,0},{0,0,0,0}};
#pragma unroll
    for (int kg = 0; kg < 4; kg++){
      const short8 b0 = ld8(&Ks[kg * 16 + l16][quad * 8]);
      const short8 b1 = ld8(&Ks[kg * 16 + l16][32 + quad * 8]);
      c[kg] = __builtin_amdgcn_mfma_f32_16x16x32_bf16(qa0, b0, c[kg], 0, 0, 0);
      c[kg] = __builtin_amdgcn_mfma_f32_16x16x32_bf16(qa1, b1, c[kg], 0, 0, 0);
    }
    // ---- causal mask (tiles at/past this wave's diagonal) ----
    if (kt0 + 63 > qw0){
#pragma unroll
      for (int kg = 0; kg < 4; kg++)
#pragma unroll
        for (int r = 0; r < 4; r++){
          const int qq = qw0 + quad * 4 + r;
          if (kt0 + kg * 16 + l16 > qq) c[kg][r] = -1e30f;
        }
    }
    // ---- fixed-m softmax: p = exp(s - 0.25); accumulate per-lane l partials ----
#pragma unroll
    for (int kg = 0; kg < 4; kg++)
#pragma unroll
      for (int r = 0; r < 4; r++) c[kg][r] = __expf(c[kg][r] - 0.25f);
#pragma unroll
    for (int r = 0; r < 4; r++)
      lpart[r] += (c[0][r] + c[1][r]) + (c[2][r] + c[3][r]);
    // ---- P -> LDS (C-layout) -> A-frags (same-wave round trip, no barrier) ----
#pragma unroll
    for (int kg = 0; kg < 4; kg++)
#pragma unroll
      for (int r = 0; r < 4; r++)
        Ps[w][quad * 4 + r][kg * 16 + l16] = f2bf(c[kg][r]);
    const short8 pa0 = ld8(&Ps[w][l16][quad * 8]);
    const short8 pa1 = ld8(&Ps[w][l16][32 + quad * 8]);
    // ---- O += P V ----
#pragma unroll
    for (int f = 0; f < 4; f++){
      const short8 vb0 = ld8(&Vt[f * 16 + l16][quad * 8]);
      const short8 vb1 = ld8(&Vt[f * 16 + l16][32 + quad * 8]);
      oacc[f] = __builtin_amdgcn_mfma_f32_16x16x32_bf16(pa0, vb0, oacc[f], 0, 0, 0);
      oacc[f] = __builtin_amdgcn_mfma_f32_16x16x32_bf16(pa1, vb1, oacc[f], 0, 0, 0);
    }
    __syncthreads();
  }
  // ---- epilogue: reduce l partials across the 16 col-lanes, scale, store ----
#pragma unroll
  for (int r = 0; r < 4; r++){
    float l = lpart[r];
#pragma unroll
    for (int o = 1; o <= 8; o <<= 1) l += __shfl_xor(l, o);
    const float inv = 1.f / l;
    const long row = base_bh + (long)(qw0 + quad * 4 + r) * strideT + l16;
#pragma unroll
    for (int f = 0; f < 4; f++) O[row + f * 16] = f2bf(oacc[f][r] * inv);
  }
}

extern "C" void kernel_launch(void* const* d_in, const int* in_sizes, int n_in,
                              void* d_out, int out_size, void* d_ws, size_t ws_size,
                              hipStream_t stream){
  const float* x       = (const float*)d_in[0];
  const float* Wq      = (const float*)d_in[1];
  const float* Wk      = (const float*)d_in[2];
  const float* Wv      = (const float*)d_in[3];
  const float* gate_w  = (const float*)d_in[4];
  const float* gate_b  = (const float*)d_in[5];
  const float* p_w     = (const float*)d_in[6];
  const float* p_b     = (const float*)d_in[7];
  const float* out_w   = (const float*)d_in[8];
  const float* out_b   = (const float*)d_in[9];
  const float* clock_w = (const float*)d_in[10];
  const float* clock_b = (const float*)d_in[11];
  const float* ln1_g   = (const float*)d_in[12];
  const float* ln1_b   = (const float*)d_in[13];
  const float* ln2_g   = (const float*)d_in[14];
  const float* ln2_b   = (const float*)d_in[15];
  const float* mlp_w1  = (const float*)d_in[16];
  const float* mlp_b1  = (const float*)d_in[17];
  const float* mlp_w2  = (const float*)d_in[18];
  const float* mlp_b2  = (const float*)d_in[19];
  float* outp = (float*)d_out;

  // ---- workspace layout (round-8-proven liveness) ----
  float* ws   = (float*)d_ws;
  float* C5   = ws;                     // slots 0..4 f32: Qb,Kb,Vf,Gb,Pb
  float* Qb   = ws;
  float* Kb   = ws + 4194304;
  float* Vf   = ws + 8388608;
  float* Gb   = ws + 12582912;
  float* Pb   = ws + 16777216;          // later X1
  float* CLKr = ws + 20971520;          // slot 5 (row*16 layout)
  float* cmax = CLKr + 65536;
  float* gsum = cmax + 65536;           // psum
  float* gpre = gsum + 65536;           // ppre
  float* pmax = gpre + 65536;
  float* biascat = cmax;                // disjoint lifetime with cmax
  short* sb   = (short*)(ws + 21235712);
  short* XNb  = sb;                     // 4M shorts (LN1 out); Vh overlay after proj
  short* Vh   = sb;                     //   written by scan_p1 (XNb dead by then)
  short* WcT  = sb + 4194304;           // concat [5136][1024] bf16 (q,k,v,gate,p,clock)
  short* OwT  = WcT + 5260288;          // 1M
  short* W1T  = OwT + 1048576;          // 4M [4096][1024]
  short* W2T  = W1T + 4194304;          // 4M [1024][4096]
  // overlays of the V f32 slot [8388608, 12582912) — written in scan_p5, V f32 dead:
  short* Qh  = (short*)(ws + 8388608);            // 8MB
  short* Kh  = (short*)(ws + 8388608 + 2097152);  // 8MB
  // other overlays:
  short* MID = (short*)ws;                        // 16M shorts over Qb+Kb
  short* Ob  = (short*)(ws + 12582912);           // over dead Gb (first 8MB)
  short* Hb  = (short*)(ws + 12582912 + 2097152); // over dead Gb (second 8MB)
  float* X1  = Pb;

  // ---- weight convert+transpose (bf16, [N][K]) ----
  wt6_kernel<<<dim3(32, 32, 6), 256, 0, stream>>>(
      Wq, Wk, Wv, gate_w, p_w, out_w,
      WcT, WcT + 1048576, WcT + 2097152, WcT + 3145728, WcT + 4194304, OwT);
  wt_kernel<<<dim3(1, 32), 256, 0, stream>>>(clock_w, WcT + 5242880, DM, NH);
  wt_kernel<<<dim3(128, 32), 256, 0, stream>>>(mlp_w1, W1T, DM, 4 * DM);
  wt_kernel<<<dim3(32, 128), 256, 0, stream>>>(mlp_w2, W2T, 4 * DM, DM);
  biascat_fill<<<21, 256, 0, stream>>>(gate_b, p_b, clock_b, biascat);

  ln_kernel<<<BT, 256, 0, stream>>>(x, ln1_g, ln1_b, XNb);

  // fused Q/K/V/gate/p/clock projection: N = 5136, scatter epilogue (128^2 tiles)
  gemm_bt<5><<<dim3(41, BT / 128), 256, 0, stream>>>(
      XNb, WcT, biascat, nullptr, nullptr, nullptr, C5, nullptr, BT, 5136, DM);

  scan_p1<<<256, 256, 0, stream>>>(Gb, Pb, Vf, Vh, cmax, gsum);
  scan_p2<<<8, 256, 0, stream>>>(cmax, gsum, pmax, gpre);
  scan_p3<<<256, 256, 0, stream>>>(Gb, Pb, CLKr, Qb, Kb, pmax, gpre, gsum);
  scan_p4<<<8, 256, 0, stream>>>(gsum, gpre);
  scan_p5<<<256, 256, 0, stream>>>(Pb, Qb, Kb, gpre, Qh, Kh);

  // flash attention: 128-row q blocks, 8 waves (512 blocks, 2/CU)
  fattn_kernel<<<dim3(TSEQ / 128, 2 * NH), 512, 0, stream>>>(Qh, Kh, Vh, Ob);

  // out-proj: X1 = attn@out_w + out_b + x, fused init outp = X1 + mlp_b2 (128^2 tiles)
  gemm_bt<4><<<dim3(DM / 128, BT / 128), 256, 0, stream>>>(
      Ob, OwT, out_b, x, mlp_b2, outp, X1, nullptr, BT, DM, DM);
  ln_kernel<<<BT, 256, 0, stream>>>(X1, ln2_g, ln2_b, Hb);
  gemm_bt<3><<<dim3(4 * DM / 128, BT / 128), 256, 0, stream>>>(
      Hb, W1T, mlp_b1, nullptr, nullptr, nullptr, nullptr, MID, BT, 4 * DM, DM);
  // MLP2: split-K=4 (1024 wg = 4/CU), f32 HW atomics into pre-init outp
  gemm_bt<6><<<dim3(DM / 128, BT / 128, 4), 256, 0, stream>>>(
      MID, W2T, nullptr, nullptr, nullptr, nullptr, outp, nullptr, BT, DM, 4 * DM);
}

// Round 11
// 569.923 us; speedup vs baseline: 1.1332x; 1.0599x over previous
//
#include <hip/hip_runtime.h>
#include <hip/hip_bf16.h>
#include <math.h>

typedef __hip_bfloat16 bf16;
typedef __attribute__((ext_vector_type(8))) short short8;
typedef __attribute__((ext_vector_type(4))) short short4v;
typedef __attribute__((ext_vector_type(4))) float f32x4;

#define BT   4096   // B*T rows
#define DM   1024
#define NH   16
#define DH   64
#define TSEQ 2048

__device__ __forceinline__ float wave_sum(float v){
#pragma unroll
  for (int o = 32; o; o >>= 1) v += __shfl_xor(v, o);
  return v;
}

__device__ __forceinline__ float block_sum(float v){
  __shared__ float sm[4];
  v = wave_sum(v);
  __syncthreads();
  if ((threadIdx.x & 63) == 0) sm[threadIdx.x >> 6] = v;
  __syncthreads();
  return sm[0] + sm[1] + sm[2] + sm[3];
}

__device__ __forceinline__ float softplusf(float x){
  return x > 20.f ? x : __logf(1.f + __expf(x));   // fast: |err| ~1e-6, tol 0.03
}

__device__ __forceinline__ short f2bf(float f){
  unsigned u = __builtin_bit_cast(unsigned, f);
  u += 0x7FFF + ((u >> 16) & 1);          // RNE; inputs finite
  return (short)(u >> 16);
}

__device__ __forceinline__ short8 ld8(const short* p){  // two 8B LDS reads
  short4v a = *(const short4v*)p;
  short4v b = *(const short4v*)(p + 4);
  short8 r;
  r[0]=a[0]; r[1]=a[1]; r[2]=a[2]; r[3]=a[3];
  r[4]=b[0]; r[5]=b[1]; r[6]=b[2]; r[7]=b[3];
  return r;
}

__device__ __forceinline__ void async16(const short* g, short* l){
  __builtin_amdgcn_global_load_lds(
      (const __attribute__((address_space(1))) void*)g,
      (__attribute__((address_space(3))) void*)l, 16, 0, 0);
}

// Bijective XCD chunk swizzle (m204): XCD k (= lin%8 under round-robin dispatch)
// processes a contiguous range of logical workgroup ids -> L2-local panel reuse.
__device__ __forceinline__ int xcd_swizzle(int lin, int nwg){
  const int q = nwg >> 3, r = nwg & 7;
  const int xcd = lin & 7, i = lin >> 3;
  return (xcd < r ? xcd * (q + 1) : r * (q + 1) + (xcd - r) * q) + i;
}

// ---------------- weight convert+transpose: f32 [K][N] -> bf16 [N][K] ----------------
__device__ __forceinline__ void wt_body(const float* __restrict__ src,
    short* __restrict__ dst, int K, int N){
  __shared__ short T[32][33];
  const int tx = threadIdx.x & 31, ty = threadIdx.x >> 5;  // ty 0..7
  const int n0 = blockIdx.x << 5, k0 = blockIdx.y << 5;
#pragma unroll
  for (int r = 0; r < 4; r++){
    const int k = k0 + (ty << 2) + r;
    const int n = n0 + tx;
    T[tx][(ty << 2) + r] = (n < N) ? f2bf(src[(long)k * N + n]) : (short)0;
  }
  __syncthreads();
#pragma unroll
  for (int r = 0; r < 4; r++){
    const int n = n0 + (ty << 2) + r;
    if (n < N) dst[(long)n * K + k0 + tx] = T[(ty << 2) + r][tx];
  }
}

__global__ __launch_bounds__(256) void wt_kernel(const float* __restrict__ src,
    short* __restrict__ dst, int K, int N){
  wt_body(src, dst, K, N);
}

// six same-shape (1024x1024) weight transposes in one launch (z selects slot)
__global__ __launch_bounds__(256) void wt6_kernel(
    const float* s0, const float* s1, const float* s2, const float* s3,
    const float* s4, const float* s5,
    short* d0, short* d1, short* d2, short* d3, short* d4, short* d5){
  const float* src; short* dst;
  switch (blockIdx.z){
    case 0: src = s0; dst = d0; break;
    case 1: src = s1; dst = d1; break;
    case 2: src = s2; dst = d2; break;
    case 3: src = s3; dst = d3; break;
    case 4: src = s4; dst = d4; break;
    default: src = s5; dst = d5; break;
  }
  wt_body(src, dst, DM, DM);
}

// ------- bias concat fill: [0..3071]=0, gate_b, p_b, clock_b (5136 entries) -------
__global__ __launch_bounds__(256) void biascat_fill(const float* __restrict__ gb,
    const float* __restrict__ pb, const float* __restrict__ cb, float* __restrict__ out){
  const int i = blockIdx.x * 256 + threadIdx.x;
  if (i >= 5136) return;
  float v = 0.f;
  if (i >= 5120) v = cb[i - 5120];
  else if (i >= 4096) v = pb[i - 4096];
  else if (i >= 3072) v = gb[i - 3072];
  out[i] = v;
}

// ---------------- LayerNorm: one block per row of 1024, bf16 out ----------------
__global__ __launch_bounds__(256) void ln_kernel(const float* __restrict__ xin,
    const float* __restrict__ g, const float* __restrict__ bb, short* __restrict__ out){
  const long row = blockIdx.x;
  const int tid = threadIdx.x;
  float v[4];
#pragma unroll
  for (int i = 0; i < 4; i++) v[i] = xin[row * DM + tid + i * 256];
  float s = block_sum(v[0] + v[1] + v[2] + v[3]);
  const float mu = s * (1.f / DM);
  float d2 = 0.f;
#pragma unroll
  for (int i = 0; i < 4; i++){ float dd = v[i] - mu; d2 = fmaf(dd, dd, d2); }
  d2 = block_sum(d2);
  const float rstd = rsqrtf(d2 * (1.f / DM) + 1e-5f);
#pragma unroll
  for (int i = 0; i < 4; i++){
    int c = tid + i * 256;
    out[row * DM + c] = f2bf(fmaf((v[i] - mu) * rstd, g[c], bb[c]));
  }
}

// ---------------- MFMA GEMM: C[M,N] = A[M,K](bf16) @ Bt[N,K]^T(bf16) + epilogue ------
// R6-proven config (636us pipeline): 128x128 tile, 4 waves, wave-tile 64x64.
// EPI: 0 Cf=v | 1 Cf=v+bias | 2 Cf=v+bias+resf | 3 Cbf=bf16(gelu(v+bias))
//      4 Cf=v+bias+resf AND Cf2=Cf+bias2 | 5 proj-scatter (N=5136)
//      6 split-K partial: atomicAdd into Cf (pre-initialized)
// K-loop: depth-2 software pipeline (3 LDS buffers), counted vmcnt, 1 barrier/step.
// Grid: bijective XCD swizzle. LDS: 16B-chunk XOR swizzle -> conflicts = 0 (R4-proven).
template <int EPI>
__global__ __launch_bounds__(256) void gemm_bt(
    const short* __restrict__ A, const short* __restrict__ Bt,
    const float* __restrict__ bias, const float* __restrict__ resf,
    const float* __restrict__ bias2, float* __restrict__ Cf2,
    float* __restrict__ Cf, short* __restrict__ Cbf, int M, int N, int K)
{
  __shared__ __attribute__((aligned(16))) short As[3][4096];
  __shared__ __attribute__((aligned(16))) short Bs[3][4096];
  const int tid = threadIdx.x;
  const int lane = tid & 63, w = tid >> 6;
  const int l16 = lane & 15, quad = lane >> 4;
  const int wm = w >> 1, wn = w & 1;
  const int gx = (int)gridDim.x, gy = (int)gridDim.y;
  int wg = xcd_swizzle((int)blockIdx.x + gx * ((int)blockIdx.y + gy * (int)blockIdx.z),
                       gx * gy * (int)gridDim.z);
  const int bx = wg % gx; wg /= gx;
  const int by = wg % gy; wg /= gy;
  const int bz = wg;
  const int bm0 = by << 7, bn0 = bx << 7;
  const int ks = K / (int)gridDim.z;
  const int kbeg = bz * ks;
  const int nt = ks >> 5;                    // number of 32-wide K-steps

  const int csw = (tid >> 3) & 3;            // = (lds_row>>1)&3 for both chunks
  const int r0 = tid >> 2,        c0 = (tid & 3) ^ csw;
  const int r1 = 64 + (tid >> 2);            // second chunk row (same csw)
  const short* ga0 = A  + (long)(bm0 + r0) * K + kbeg + c0 * 8;
  const short* ga1 = A  + (long)(bm0 + r1) * K + kbeg + c0 * 8;
  const short* gb0 = Bt + (long)min(bn0 + r0, N - 1) * K + kbeg + c0 * 8;
  const short* gb1 = Bt + (long)min(bn0 + r1, N - 1) * K + kbeg + c0 * 8;
  const int wofs = w << 9;                   // per-wave LDS base (shorts)

#define STAGE(buf, t) do {                                   \
    const long ko_ = (long)(t) * 32;                         \
    async16(ga0 + ko_, &As[buf][wofs]);                      \
    async16(gb0 + ko_, &Bs[buf][wofs]);                      \
    async16(ga1 + ko_, &As[buf][2048 + wofs]);               \
    async16(gb1 + ko_, &Bs[buf][2048 + wofs]);               \
  } while (0)

  f32x4 acc[4][4] = {};

  STAGE(0, 0);
  if (nt > 1) STAGE(1, 1);

  const int qsw = (quad ^ ((l16 >> 1) & 3)) * 8;

  int cur = 0, stg = 2;
  for (int t = 0; t < nt; t++){
    if (t + 1 < nt){
      asm volatile("s_waitcnt vmcnt(4)" ::: "memory");   // tile t staged 2 phases ago
    } else {
      asm volatile("s_waitcnt vmcnt(0)" ::: "memory");   // last tile: drain
    }
    __builtin_amdgcn_s_barrier();
    __builtin_amdgcn_sched_barrier(0);       // pin: no ds_read/stage hoists above barrier
    if (t + 2 < nt) STAGE(stg, t + 2);       // buffer stg was last read at iter t-1
    short8 af[4], bfr[4];
#pragma unroll
    for (int i = 0; i < 4; i++){
      af[i]  = *(const short8*)&As[cur][(wm * 64 + i * 16 + l16) * 32 + qsw];
      bfr[i] = *(const short8*)&Bs[cur][(wn * 64 + i * 16 + l16) * 32 + qsw];
    }
#pragma unroll
    for (int i = 0; i < 4; i++)
#pragma unroll
      for (int j = 0; j < 4; j++)
        acc[i][j] = __builtin_amdgcn_mfma_f32_16x16x32_bf16(af[i], bfr[j], acc[i][j], 0, 0, 0);
    cur = (cur == 2) ? 0 : cur + 1;
    stg = (stg == 2) ? 0 : stg + 1;
  }
#undef STAGE

#pragma unroll
  for (int i = 0; i < 4; i++){
#pragma unroll
    for (int r = 0; r < 4; r++){
      const int row = bm0 + wm * 64 + i * 16 + quad * 4 + r;
#pragma unroll
      for (int j = 0; j < 4; j++){
        const int col = bn0 + wn * 64 + j * 16 + l16;
        if (col < N){
          float v = acc[i][j][r];
          const long off = (long)row * N + col;
          if constexpr (EPI >= 1 && EPI != 6) v += bias[col];
          if constexpr (EPI == 2 || EPI == 4) v += resf[off];
          if constexpr (EPI == 3){
            v = 0.5f * v * (1.f + erff(v * 0.70710678118654752f));
            Cbf[off] = f2bf(v);
          } else if constexpr (EPI == 4){
            Cf[off] = v;
            Cf2[off] = v + bias2[col];
          } else if constexpr (EPI == 5){
            if (col < 5120)
              Cf[(long)(col >> 10) * 4194304 + (long)row * 1024 + (col & 1023)] = v;
            else
              Cf[20971520 + (long)row * 16 + (col - 5120)] = v;   // CLKr (slot 5)
          } else if constexpr (EPI == 6){
            unsafeAtomicAdd(&Cf[off], v);     // global_atomic_add_f32, device scope
          } else {
            Cf[off] = v;
          }
        }
      }
    }
  }
}

// ---------------- Chunked scans over T (32 chunks x 64) ----------------
// Serial loops strip-mined into batches of 8: each batch issues 8 independent
// loads per array up-front (ILP-8) -- pays HBM latency once per 8 iterations
// instead of per iteration (scans run at 4 waves/CU: no TLP to hide latency).
// p1 also converts V f32 -> bf16 Vh (XNb overlay; XNb dead after proj GEMM)
__global__ __launch_bounds__(256) void scan_p1(float* __restrict__ G, const float* __restrict__ P,
    const float* __restrict__ Vf, short* __restrict__ Vh,
    float* __restrict__ cmax, float* __restrict__ gsum){
  const int tid = blockIdx.x * 256 + threadIdx.x;    // 65536
  const int d = tid & 63, c = (tid >> 6) & 31, bh = tid >> 11;
  const int h = bh & 15, b = bh >> 4;
  const long base = (((long)(b * TSEQ + c * 64)) * NH + h) * 64 + d;
  const long str = NH * 64;
  float mx = -1e30f, gs = 0.f;
  for (int tb = 0; tb < 8; tb++){
    float g[8], p[8], v[8];
#pragma unroll
    for (int j = 0; j < 8; j++){
      const long idx = base + (long)(tb * 8 + j) * str;
      g[j] = G[idx]; p[j] = P[idx]; v[j] = Vf[idx];
    }
#pragma unroll
    for (int j = 0; j < 8; j++){
      const long idx = base + (long)(tb * 8 + j) * str;
      float gj = -softplusf(g[j]);
      G[idx] = gj;
      gs += gj;
      mx = fmaxf(mx, p[j]);
      Vh[idx] = f2bf(v[j]);
    }
  }
  const int chain = bh * 64 + d;
  cmax[chain * 32 + c] = mx;
  gsum[chain * 32 + c] = gs;
}

__global__ void scan_p2(const float* __restrict__ cmax, const float* __restrict__ gsum,
                        float* __restrict__ pmax, float* __restrict__ gpre){
  const int chain = blockIdx.x * 256 + threadIdx.x;  // 2048
  const f32x4* cm4 = (const f32x4*)(cmax + chain * 32);
  const f32x4* gs4 = (const f32x4*)(gsum + chain * 32);
  f32x4* gp4 = (f32x4*)(gpre + chain * 32);
  f32x4 cv[8], gv[8];
#pragma unroll
  for (int i = 0; i < 8; i++){ cv[i] = cm4[i]; gv[i] = gs4[i]; }
  float mx = -1e30f;
#pragma unroll
  for (int i = 0; i < 8; i++)
    mx = fmaxf(mx, fmaxf(fmaxf(cv[i][0], cv[i][1]), fmaxf(cv[i][2], cv[i][3])));
  pmax[chain] = mx;
  float run = 0.f;
#pragma unroll
  for (int i = 0; i < 8; i++){
    f32x4 o;
#pragma unroll
    for (int j = 0; j < 4; j++){ o[j] = run; run += gv[i][j]; }
    gp4[i] = o;
  }
}

// p3 also applies l2norm + RoPE to Q,K (wave lanes == the 64 d-values of one row)
// trig: exact sinf/cosf once per chunk, then incremental angle rotation (4 FMA/step;
// drift ~6e-5 over 63 steps, tol 0.03). Batched ILP-8 loads; rsqrt/rcp fast math.
__global__ __launch_bounds__(256) void scan_p3(const float* __restrict__ G, float* __restrict__ P,
    const float* __restrict__ CLKr, float* __restrict__ Q, float* __restrict__ K,
    const float* __restrict__ pmax, const float* __restrict__ gpre, float* __restrict__ psum){
  const int tid = blockIdx.x * 256 + threadIdx.x;
  const int d = tid & 63, c = (tid >> 6) & 31, bh = tid >> 11;
  const int h = bh & 15, b = bh >> 4;
  const int chain = bh * 64 + d;
  const long base = (((long)(b * TSEQ + c * 64)) * NH + h) * 64 + d;
  const long str = NH * 64;
  const float pm = pmax[chain];
  const float freq = expf(-(float)(d >> 1) * 0.28782313662425575f); // ln(1e4)/32
  // incremental rotation state: angle th = t*freq, t starts at c*64
  float sn = sinf((float)(c * 64) * freq);
  float cn = cosf((float)(c * 64) * freq);
  const float sf = sinf(freq), cf = cosf(freq);
  float grun = gpre[chain * 32 + c];
  float ps = 0.f;
  for (int tb = 0; tb < 8; tb++){
    float g[8], p[8], q[8], k[8], ck[8];
#pragma unroll
    for (int j = 0; j < 8; j++){
      const long idx = base + (long)(tb * 8 + j) * str;
      g[j] = G[idx]; p[j] = P[idx]; q[j] = Q[idx]; k[j] = K[idx];
      const int t = c * 64 + tb * 8 + j;
      ck[j] = CLKr[(long)(b * TSEQ + t) * NH + h];
    }
#pragma unroll
    for (int j = 0; j < 8; j++){
      const long idx = base + (long)(tb * 8 + j) * str;
      float clk = softplusf(ck[j]);
      float pe = __expf(p[j] - pm) * clk;
      P[idx] = pe; ps += pe;
      grun += g[j];
      float gc = __expf(fminf(fmaxf(grun, -60.f), 50.f));
      {
        float qq = q[j];
        float s2 = wave_sum(qq * qq);
        qq *= rsqrtf(fmaxf(s2, 1e-24f));       // == q / max(sqrt(s2), 1e-12)
        float pr = __shfl_xor(qq, 1);
        qq = (d & 1) ? fmaf(pr, sn, qq * cn) : fmaf(qq, cn, -pr * sn);
        Q[idx] = qq * gc;
      }
      {
        float kk = k[j];
        float s2 = wave_sum(kk * kk);
        kk *= rsqrtf(fmaxf(s2, 1e-24f));
        float pr = __shfl_xor(kk, 1);
        kk = (d & 1) ? fmaf(pr, sn, kk * cn) : fmaf(kk, cn, -pr * sn);
        K[idx] = kk * __builtin_amdgcn_rcpf(gc + 1e-8f);
      }
      // rotate (sn,cn) by freq
      const float ns = fmaf(sn, cf, cn * sf);
      const float nc = fmaf(cn, cf, -sn * sf);
      sn = ns; cn = nc;
    }
  }
  psum[chain * 32 + c] = ps;
}

__global__ void scan_p4(const float* __restrict__ psum, float* __restrict__ ppre){
  const int chain = blockIdx.x * 256 + threadIdx.x;
  const f32x4* ps4 = (const f32x4*)(psum + chain * 32);
  f32x4* pp4 = (f32x4*)(ppre + chain * 32);
  f32x4 pv[8];
#pragma unroll
  for (int i = 0; i < 8; i++) pv[i] = ps4[i];
  float run = 0.f;
#pragma unroll
  for (int i = 0; i < 8; i++){
    f32x4 o;
#pragma unroll
    for (int j = 0; j < 4; j++){ o[j] = run; run += pv[i][j]; }
    pp4[i] = o;
  }
}

// final scan: emits bf16 Qh (pre-scaled by 0.125) and bf16 Kh (V f32 dead by now)
__global__ __launch_bounds__(256) void scan_p5(const float* __restrict__ P, const float* __restrict__ Q,
    const float* __restrict__ K, const float* __restrict__ ppre,
    short* __restrict__ Qh, short* __restrict__ Kh){
  const int tid = blockIdx.x * 256 + threadIdx.x;
  const int d = tid & 63, c = (tid >> 6) & 31, bh = tid >> 11;
  const int h = bh & 15, b = bh >> 4;
  const int chain = bh * 64 + d;
  const long base = (((long)(b * TSEQ + c * 64)) * NH + h) * 64 + d;
  const long str = NH * 64;
  float cs = ppre[chain * 32 + c];
  for (int tb = 0; tb < 8; tb++){
    float p[8], q[8], k[8];
#pragma unroll
    for (int j = 0; j < 8; j++){
      const long idx = base + (long)(tb * 8 + j) * str;
      p[j] = P[idx]; q[j] = Q[idx]; k[j] = K[idx];
    }
#pragma unroll
    for (int j = 0; j < 8; j++){
      const long idx = base + (long)(tb * 8 + j) * str;
      cs += p[j];
      Qh[idx] = f2bf(q[j] * 0.125f * __builtin_amdgcn_rcpf(cs + 1e-8f));
      Kh[idx] = f2bf(k[j] * p[j]);
    }
  }
}

// ------- MFMA flash attention v2: 128-row Q blocks, 8 waves sharing one K/V staging.
// Tile-iterations halve vs the 64-row version (Sum(2qt+2)=272 vs Sum(qt+1)=528 per bh):
// half the staging stores, barriers, and prefetch loads; per-wave MFMA work unchanged.
// Fixed-m softmax (|s|<=0.125 < 0.25), deferred l, register prefetch, bf16 in/out. -------
__global__ __launch_bounds__(512, 2) void fattn_kernel(const short* __restrict__ Qh,
    const short* __restrict__ Kh, const short* __restrict__ Vh, short* __restrict__ O){
  __shared__ __attribute__((aligned(16))) short Ks[64][72];   // [key][d]
  __shared__ __attribute__((aligned(16))) short Vt[64][68];   // [d][key]
  __shared__ __attribute__((aligned(16))) short Ps[8][16][72];
  const int tid  = threadIdx.x;
  const int lane = tid & 63, w = tid >> 6;            // 8 waves x 16 q-rows
  const int quad = lane >> 4, l16 = lane & 15;
  // XCD swizzle keeps a (b,h)'s q-tiles on one XCD (K/V L2 reuse).
  const int gx = (int)gridDim.x;                      // 16
  int wgs = xcd_swizzle((int)blockIdx.x + gx * (int)blockIdx.y, gx * (int)gridDim.y);
  const int bxs = wgs % gx;
  const int bh = wgs / gx, h = bh & 15, b = bh >> 4;
  // qt order alternates by (bh>>1) parity: co-resident CU block pairs sum ~const work.
  const int qt = ((bh >> 1) & 1) ? bxs : (gx - 1 - bxs);
  const int q0  = qt << 7;
  const int qw0 = q0 + w * 16;
  const long strideT = NH * DH;
  const long base_bh = ((long)b * TSEQ * NH + h) * DH;

  const short* qp = Qh + base_bh + (long)(qw0 + l16) * strideT + quad * 8;
  const short8 qa0 = *(const short8*)qp;
  const short8 qa1 = *(const short8*)(qp + 32);

  f32x4 oacc[4] = {{0,0,0,0},{0,0,0,0},{0,0,0,0},{0,0,0,0}};
  float lpart[4] = {0.f,0.f,0.f,0.f};    // per-lane partial row sums (fixed m)

  // staging split across 512 threads: K 64x64 shorts (1 short8/thread),
  // V transpose 8 d-values/thread (w = d-group).
  const int krow = tid >> 3, kcol = (tid & 7) << 3;
  const int vkey = tid & 63, vd0 = w << 3;
  const short* kbase = Kh + base_bh + (long)krow * strideT + kcol;
  const short* vbase = Vh + base_bh + (long)vkey * strideT + vd0;

  // prefetch tile 0 into registers
  short8 kr0 = *(const short8*)kbase;
  short8 vr0 = *(const short8*)vbase;

  const int ntiles = 2 * qt + 2;          // keys 0 .. q0+127 covered
  for (int t = 0; t < ntiles; t++){
    // commit prefetched tile to LDS
    *(short8*)&Ks[krow][kcol] = kr0;
#pragma unroll
    for (int j = 0; j < 8; j++) Vt[vd0 + j][vkey] = vr0[j];
    __syncthreads();
    // issue next tile's loads (overlap with compute)
    if (t + 1 < ntiles){
      const long off = (long)(t + 1) * (64 * strideT);
      kr0 = *(const short8*)(kbase + off);
      vr0 = *(const short8*)(vbase + off);
    }
    const int kt0 = t << 6;
    // ---- S = Q K^T ----
    f32x4 c[4] = {{0,0,0,0},{0,0,0,0},{0,0,0,0},{0,0,0,0}};
#pragma unroll
    for (int kg = 0; kg < 4; kg++){
      const short8 b0 = ld8(&Ks[kg * 16 + l16][quad * 8]);
      const short8 b1 = ld8(&Ks[kg * 16 + l16][32 + quad * 8]);
      c[kg] = __builtin_amdgcn_mfma_f32_16x16x32_bf16(qa0, b0, c[kg], 0, 0, 0);
      c[kg] = __builtin_amdgcn_mfma_f32_16x16x32_bf16(qa1, b1, c[kg], 0, 0, 0);
    }
    // ---- causal mask (tiles at/past this wave's diagonal) ----
    if (kt0 + 63 > qw0){
#pragma unroll
      for (int kg = 0; kg < 4; kg++)
#pragma unroll
        for (int r = 0; r < 4; r++){
          const int qq = qw0 + quad * 4 + r;
          if (kt0 + kg * 16 + l16 > qq) c[kg][r] = -1e30f;
        }
    }
    // ---- fixed-m softmax: p = exp(s - 0.25); accumulate per-lane l partials ----
#pragma unroll
    for (int kg = 0; kg < 4; kg++)
#pragma unroll
      for (int r = 0; r < 4; r++) c[kg][r] = __expf(c[kg][r] - 0.25f);
#pragma unroll
    for (int r = 0; r < 4; r++)
      lpart[r] += (c[0][r] + c[1][r]) + (c[2][r] + c[3][r]);
    // ---- P -> LDS (C-layout) -> A-frags (same-wave round trip, no barrier) ----
#pragma unroll
    for (int kg = 0; kg < 4; kg++)
#pragma unroll
      for (int r = 0; r < 4; r++)
        Ps[w][quad * 4 + r][kg * 16 + l16] = f2bf(c[kg][r]);
    const short8 pa0 = ld8(&Ps[w][l16][quad * 8]);
    const short8 pa1 = ld8(&Ps[w][l16][32 + quad * 8]);
    // ---- O += P V ----
#pragma unroll
    for (int f = 0; f < 4; f++){
      const short8 vb0 = ld8(&Vt[f * 16 + l16][quad * 8]);
      const short8 vb1 = ld8(&Vt[f * 16 + l16][32 + quad * 8]);
      oacc[f] = __builtin_amdgcn_mfma_f32_16x16x32_bf16(pa0, vb0, oacc[f], 0, 0, 0);
      oacc[f] = __builtin_amdgcn_mfma_f32_16x16x32_bf16(pa1, vb1, oacc[f], 0, 0, 0);
    }
    __syncthreads();
  }
  // ---- epilogue: reduce l partials across the 16 col-lanes, scale, store ----
#pragma unroll
  for (int r = 0; r < 4; r++){
    float l = lpart[r];
#pragma unroll
    for (int o = 1; o <= 8; o <<= 1) l += __shfl_xor(l, o);
    const float inv = 1.f / l;
    const long row = base_bh + (long)(qw0 + quad * 4 + r) * strideT + l16;
#pragma unroll
    for (int f = 0; f < 4; f++) O[row + f * 16] = f2bf(oacc[f][r] * inv);
  }
}

extern "C" void kernel_launch(void* const* d_in, const int* in_sizes, int n_in,
                              void* d_out, int out_size, void* d_ws, size_t ws_size,
                              hipStream_t stream){
  const float* x       = (const float*)d_in[0];
  const float* Wq      = (const float*)d_in[1];
  const float* Wk      = (const float*)d_in[2];
  const float* Wv      = (const float*)d_in[3];
  const float* gate_w  = (const float*)d_in[4];
  const float* gate_b  = (const float*)d_in[5];
  const float* p_w     = (const float*)d_in[6];
  const float* p_b     = (const float*)d_in[7];
  const float* out_w   = (const float*)d_in[8];
  const float* out_b   = (const float*)d_in[9];
  const float* clock_w = (const float*)d_in[10];
  const float* clock_b = (const float*)d_in[11];
  const float* ln1_g   = (const float*)d_in[12];
  const float* ln1_b   = (const float*)d_in[13];
  const float* ln2_g   = (const float*)d_in[14];
  const float* ln2_b   = (const float*)d_in[15];
  const float* mlp_w1  = (const float*)d_in[16];
  const float* mlp_b1  = (const float*)d_in[17];
  const float* mlp_w2  = (const float*)d_in[18];
  const float* mlp_b2  = (const float*)d_in[19];
  float* outp = (float*)d_out;

  // ---- workspace layout (round-8-proven liveness) ----
  float* ws   = (float*)d_ws;
  float* C5   = ws;                     // slots 0..4 f32: Qb,Kb,Vf,Gb,Pb
  float* Qb   = ws;
  float* Kb   = ws + 4194304;
  float* Vf   = ws + 8388608;
  float* Gb   = ws + 12582912;
  float* Pb   = ws + 16777216;          // later X1
  float* CLKr = ws + 20971520;          // slot 5 (row*16 layout)
  float* cmax = CLKr + 65536;
  float* gsum = cmax + 65536;           // psum
  float* gpre = gsum + 65536;           // ppre
  float* pmax = gpre + 65536;
  float* biascat = cmax;                // disjoint lifetime with cmax
  short* sb   = (short*)(ws + 21235712);
  short* XNb  = sb;                     // 4M shorts (LN1 out); Vh overlay after proj
  short* Vh   = sb;                     //   written by scan_p1 (XNb dead by then)
  short* WcT  = sb + 4194304;           // concat [5136][1024] bf16 (q,k,v,gate,p,clock)
  short* OwT  = WcT + 5260288;          // 1M
  short* W1T  = OwT + 1048576;          // 4M [4096][1024]
  short* W2T  = W1T + 4194304;          // 4M [1024][4096]
  // overlays of the V f32 slot [8388608, 12582912) — written in scan_p5, V f32 dead:
  short* Qh  = (short*)(ws + 8388608);            // 8MB
  short* Kh  = (short*)(ws + 8388608 + 2097152);  // 8MB
  // other overlays:
  short* MID = (short*)ws;                        // 16M shorts over Qb+Kb
  short* Ob  = (short*)(ws + 12582912);           // over dead Gb (first 8MB)
  short* Hb  = (short*)(ws + 12582912 + 2097152); // over dead Gb (second 8MB)
  float* X1  = Pb;

  // ---- weight convert+transpose (bf16, [N][K]) ----
  wt6_kernel<<<dim3(32, 32, 6), 256, 0, stream>>>(
      Wq, Wk, Wv, gate_w, p_w, out_w,
      WcT, WcT + 1048576, WcT + 2097152, WcT + 3145728, WcT + 4194304, OwT);
  wt_kernel<<<dim3(1, 32), 256, 0, stream>>>(clock_w, WcT + 5242880, DM, NH);
  wt_kernel<<<dim3(128, 32), 256, 0, stream>>>(mlp_w1, W1T, DM, 4 * DM);
  wt_kernel<<<dim3(32, 128), 256, 0, stream>>>(mlp_w2, W2T, 4 * DM, DM);
  biascat_fill<<<21, 256, 0, stream>>>(gate_b, p_b, clock_b, biascat);

  ln_kernel<<<BT, 256, 0, stream>>>(x, ln1_g, ln1_b, XNb);

  // fused Q/K/V/gate/p/clock projection: N = 5136, scatter epilogue (128^2 tiles)
  gemm_bt<5><<<dim3(41, BT / 128), 256, 0, stream>>>(
      XNb, WcT, biascat, nullptr, nullptr, nullptr, C5, nullptr, BT, 5136, DM);

  scan_p1<<<256, 256, 0, stream>>>(Gb, Pb, Vf, Vh, cmax, gsum);
  scan_p2<<<8, 256, 0, stream>>>(cmax, gsum, pmax, gpre);
  scan_p3<<<256, 256, 0, stream>>>(Gb, Pb, CLKr, Qb, Kb, pmax, gpre, gsum);
  scan_p4<<<8, 256, 0, stream>>>(gsum, gpre);
  scan_p5<<<256, 256, 0, stream>>>(Pb, Qb, Kb, gpre, Qh, Kh);

  // flash attention: 128-row q blocks, 8 waves (512 blocks, 2/CU)
  fattn_kernel<<<dim3(TSEQ / 128, 2 * NH), 512, 0, stream>>>(Qh, Kh, Vh, Ob);

  // out-proj: X1 = attn@out_w + out_b + x, fused init outp = X1 + mlp_b2 (128^2 tiles)
  gemm_bt<4><<<dim3(DM / 128, BT / 128), 256, 0, stream>>>(
      Ob, OwT, out_b, x, mlp_b2, outp, X1, nullptr, BT, DM, DM);
  ln_kernel<<<BT, 256, 0, stream>>>(X1, ln2_g, ln2_b, Hb);
  gemm_bt<3><<<dim3(4 * DM / 128, BT / 128), 256, 0, stream>>>(
      Hb, W1T, mlp_b1, nullptr, nullptr, nullptr, nullptr, MID, BT, 4 * DM, DM);
  // MLP2: split-K=4 (1024 wg = 4/CU), f32 HW atomics into pre-init outp
  gemm_bt<6><<<dim3(DM / 128, BT / 128, 4), 256, 0, stream>>>(
      MID, W2T, nullptr, nullptr, nullptr, nullptr, outp, nullptr, BT, DM, 4 * DM);
}

// Round 12
// 525.728 us; speedup vs baseline: 1.2284x; 1.0841x over previous
//
#include <hip/hip_runtime.h>
#include <hip/hip_bf16.h>
#include <math.h>

typedef __hip_bfloat16 bf16;
typedef __attribute__((ext_vector_type(8))) short short8;
typedef __attribute__((ext_vector_type(4))) short short4v;
typedef __attribute__((ext_vector_type(4))) float f32x4;

#define BT   4096   // B*T rows
#define DM   1024
#define NH   16
#define DH   64
#define TSEQ 2048

__device__ __forceinline__ float wave_sum(float v){
#pragma unroll
  for (int o = 32; o; o >>= 1) v += __shfl_xor(v, o);
  return v;
}

__device__ __forceinline__ float block_sum(float v){
  __shared__ float sm[4];
  v = wave_sum(v);
  __syncthreads();
  if ((threadIdx.x & 63) == 0) sm[threadIdx.x >> 6] = v;
  __syncthreads();
  return sm[0] + sm[1] + sm[2] + sm[3];
}

__device__ __forceinline__ float softplusf(float x){
  return x > 20.f ? x : __logf(1.f + __expf(x));   // fast: |err| ~1e-6, tol 0.03
}

__device__ __forceinline__ short f2bf(float f){
  unsigned u = __builtin_bit_cast(unsigned, f);
  u += 0x7FFF + ((u >> 16) & 1);          // RNE; inputs finite
  return (short)(u >> 16);
}

__device__ __forceinline__ short8 ld8(const short* p){  // two 8B LDS reads
  short4v a = *(const short4v*)p;
  short4v b = *(const short4v*)(p + 4);
  short8 r;
  r[0]=a[0]; r[1]=a[1]; r[2]=a[2]; r[3]=a[3];
  r[4]=b[0]; r[5]=b[1]; r[6]=b[2]; r[7]=b[3];
  return r;
}

__device__ __forceinline__ void async16(const short* g, short* l){
  __builtin_amdgcn_global_load_lds(
      (const __attribute__((address_space(1))) void*)g,
      (__attribute__((address_space(3))) void*)l, 16, 0, 0);
}

// Bijective XCD chunk swizzle (m204): XCD k (= lin%8 under round-robin dispatch)
// processes a contiguous range of logical workgroup ids -> L2-local panel reuse.
__device__ __forceinline__ int xcd_swizzle(int lin, int nwg){
  const int q = nwg >> 3, r = nwg & 7;
  const int xcd = lin & 7, i = lin >> 3;
  return (xcd < r ? xcd * (q + 1) : r * (q + 1) + (xcd - r) * q) + i;
}

// ---------------- weight convert+transpose: f32 [K][N] -> bf16 [N][K] ----------------
__device__ __forceinline__ void wt_body(const float* __restrict__ src,
    short* __restrict__ dst, int K, int N){
  __shared__ short T[32][33];
  const int tx = threadIdx.x & 31, ty = threadIdx.x >> 5;  // ty 0..7
  const int n0 = blockIdx.x << 5, k0 = blockIdx.y << 5;
#pragma unroll
  for (int r = 0; r < 4; r++){
    const int k = k0 + (ty << 2) + r;
    const int n = n0 + tx;
    T[tx][(ty << 2) + r] = (n < N) ? f2bf(src[(long)k * N + n]) : (short)0;
  }
  __syncthreads();
#pragma unroll
  for (int r = 0; r < 4; r++){
    const int n = n0 + (ty << 2) + r;
    if (n < N) dst[(long)n * K + k0 + tx] = T[(ty << 2) + r][tx];
  }
}

__global__ __launch_bounds__(256) void wt_kernel(const float* __restrict__ src,
    short* __restrict__ dst, int K, int N){
  wt_body(src, dst, K, N);
}

// six same-shape (1024x1024) weight transposes in one launch (z selects slot)
__global__ __launch_bounds__(256) void wt6_kernel(
    const float* s0, const float* s1, const float* s2, const float* s3,
    const float* s4, const float* s5,
    short* d0, short* d1, short* d2, short* d3, short* d4, short* d5){
  const float* src; short* dst;
  switch (blockIdx.z){
    case 0: src = s0; dst = d0; break;
    case 1: src = s1; dst = d1; break;
    case 2: src = s2; dst = d2; break;
    case 3: src = s3; dst = d3; break;
    case 4: src = s4; dst = d4; break;
    default: src = s5; dst = d5; break;
  }
  wt_body(src, dst, DM, DM);
}

// ------- bias concat fill: [0..3071]=0, gate_b, p_b, clock_b (5136 entries) -------
__global__ __launch_bounds__(256) void biascat_fill(const float* __restrict__ gb,
    const float* __restrict__ pb, const float* __restrict__ cb, float* __restrict__ out){
  const int i = blockIdx.x * 256 + threadIdx.x;
  if (i >= 5136) return;
  float v = 0.f;
  if (i >= 5120) v = cb[i - 5120];
  else if (i >= 4096) v = pb[i - 4096];
  else if (i >= 3072) v = gb[i - 3072];
  out[i] = v;
}

// ---------------- LayerNorm: one block per row of 1024, bf16 out ----------------
// f32x4 vectorized loads/stores (G13): thread owns cols tid*4..tid*4+3.
__global__ __launch_bounds__(256) void ln_kernel(const float* __restrict__ xin,
    const float* __restrict__ g, const float* __restrict__ bb, short* __restrict__ out){
  const long row = blockIdx.x;
  const int tid = threadIdx.x;
  const f32x4 v = ((const f32x4*)(xin + row * DM))[tid];
  float s = block_sum((v[0] + v[1]) + (v[2] + v[3]));
  const float mu = s * (1.f / DM);
  float d2 = 0.f;
#pragma unroll
  for (int i = 0; i < 4; i++){ float dd = v[i] - mu; d2 = fmaf(dd, dd, d2); }
  d2 = block_sum(d2);
  const float rstd = rsqrtf(d2 * (1.f / DM) + 1e-5f);
  const f32x4 gv = ((const f32x4*)g)[tid];
  const f32x4 bv = ((const f32x4*)bb)[tid];
  short4v o;
#pragma unroll
  for (int i = 0; i < 4; i++)
    o[i] = f2bf(fmaf((v[i] - mu) * rstd, gv[i], bv[i]));
  ((short4v*)(out + row * DM))[tid] = o;
}

// ---------------- MFMA GEMM: C[M,N] = A[M,K](bf16) @ Bt[N,K]^T(bf16) + epilogue ------
// R6-proven config: 128x128 tile, 4 waves, wave-tile 64x64.
// EPI: 0 Cf=v | 1 Cf=v+bias | 2 Cf=v+bias+resf | 3 Cbf=bf16(gelu(v+bias))
//      4 Cf=v+bias+resf AND Cf2=Cf+bias2 | 5 proj-scatter (N=5136)
//      6 split-K partial: atomicAdd into Cf (pre-initialized)
// K-loop: depth-2 software pipeline (3 LDS buffers), counted vmcnt, 1 barrier/step.
// Grid: bijective XCD swizzle. LDS: 16B-chunk XOR swizzle -> conflicts = 0 (R4-proven).
template <int EPI>
__global__ __launch_bounds__(256) void gemm_bt(
    const short* __restrict__ A, const short* __restrict__ Bt,
    const float* __restrict__ bias, const float* __restrict__ resf,
    const float* __restrict__ bias2, float* __restrict__ Cf2,
    float* __restrict__ Cf, short* __restrict__ Cbf, int M, int N, int K)
{
  __shared__ __attribute__((aligned(16))) short As[3][4096];
  __shared__ __attribute__((aligned(16))) short Bs[3][4096];
  const int tid = threadIdx.x;
  const int lane = tid & 63, w = tid >> 6;
  const int l16 = lane & 15, quad = lane >> 4;
  const int wm = w >> 1, wn = w & 1;
  const int gx = (int)gridDim.x, gy = (int)gridDim.y;
  int wg = xcd_swizzle((int)blockIdx.x + gx * ((int)blockIdx.y + gy * (int)blockIdx.z),
                       gx * gy * (int)gridDim.z);
  const int bx = wg % gx; wg /= gx;
  const int by = wg % gy; wg /= gy;
  const int bz = wg;
  const int bm0 = by << 7, bn0 = bx << 7;
  const int ks = K / (int)gridDim.z;
  const int kbeg = bz * ks;
  const int nt = ks >> 5;                    // number of 32-wide K-steps

  const int csw = (tid >> 3) & 3;            // = (lds_row>>1)&3 for both chunks
  const int r0 = tid >> 2,        c0 = (tid & 3) ^ csw;
  const int r1 = 64 + (tid >> 2);            // second chunk row (same csw)
  const short* ga0 = A  + (long)(bm0 + r0) * K + kbeg + c0 * 8;
  const short* ga1 = A  + (long)(bm0 + r1) * K + kbeg + c0 * 8;
  const short* gb0 = Bt + (long)min(bn0 + r0, N - 1) * K + kbeg + c0 * 8;
  const short* gb1 = Bt + (long)min(bn0 + r1, N - 1) * K + kbeg + c0 * 8;
  const int wofs = w << 9;                   // per-wave LDS base (shorts)

#define STAGE(buf, t) do {                                   \
    const long ko_ = (long)(t) * 32;                         \
    async16(ga0 + ko_, &As[buf][wofs]);                      \
    async16(gb0 + ko_, &Bs[buf][wofs]);                      \
    async16(ga1 + ko_, &As[buf][2048 + wofs]);               \
    async16(gb1 + ko_, &Bs[buf][2048 + wofs]);               \
  } while (0)

  f32x4 acc[4][4] = {};

  STAGE(0, 0);
  if (nt > 1) STAGE(1, 1);

  const int qsw = (quad ^ ((l16 >> 1) & 3)) * 8;

  int cur = 0, stg = 2;
  for (int t = 0; t < nt; t++){
    if (t + 1 < nt){
      asm volatile("s_waitcnt vmcnt(4)" ::: "memory");   // tile t staged 2 phases ago
    } else {
      asm volatile("s_waitcnt vmcnt(0)" ::: "memory");   // last tile: drain
    }
    __builtin_amdgcn_s_barrier();
    __builtin_amdgcn_sched_barrier(0);       // pin: no ds_read/stage hoists above barrier
    if (t + 2 < nt) STAGE(stg, t + 2);       // buffer stg was last read at iter t-1
    short8 af[4], bfr[4];
#pragma unroll
    for (int i = 0; i < 4; i++){
      af[i]  = *(const short8*)&As[cur][(wm * 64 + i * 16 + l16) * 32 + qsw];
      bfr[i] = *(const short8*)&Bs[cur][(wn * 64 + i * 16 + l16) * 32 + qsw];
    }
#pragma unroll
    for (int i = 0; i < 4; i++)
#pragma unroll
      for (int j = 0; j < 4; j++)
        acc[i][j] = __builtin_amdgcn_mfma_f32_16x16x32_bf16(af[i], bfr[j], acc[i][j], 0, 0, 0);
    cur = (cur == 2) ? 0 : cur + 1;
    stg = (stg == 2) ? 0 : stg + 1;
  }
#undef STAGE

#pragma unroll
  for (int i = 0; i < 4; i++){
#pragma unroll
    for (int r = 0; r < 4; r++){
      const int row = bm0 + wm * 64 + i * 16 + quad * 4 + r;
#pragma unroll
      for (int j = 0; j < 4; j++){
        const int col = bn0 + wn * 64 + j * 16 + l16;
        if (col < N){
          float v = acc[i][j][r];
          const long off = (long)row * N + col;
          if constexpr (EPI >= 1 && EPI != 6) v += bias[col];
          if constexpr (EPI == 2 || EPI == 4) v += resf[off];
          if constexpr (EPI == 3){
            v = 0.5f * v * (1.f + erff(v * 0.70710678118654752f));
            Cbf[off] = f2bf(v);
          } else if constexpr (EPI == 4){
            Cf[off] = v;
            Cf2[off] = v + bias2[col];
          } else if constexpr (EPI == 5){
            if (col < 5120)
              Cf[(long)(col >> 10) * 4194304 + (long)row * 1024 + (col & 1023)] = v;
            else
              Cf[20971520 + (long)row * 16 + (col - 5120)] = v;   // CLKr (slot 5)
          } else if constexpr (EPI == 6){
            unsafeAtomicAdd(&Cf[off], v);     // global_atomic_add_f32, device scope
          } else {
            Cf[off] = v;
          }
        }
      }
    }
  }
}

// ------- gemm8_gelu: 8-phase-style fine interleave (m201/m196 mechanism) -------
// 256x256 tile, BK=32, 8 waves (2M x 4N), wave-tile 128x64. 3 LDS buffers (96KB).
// TWO phases per K-tile, each = {ds_read subtile || stage 2 gload_lds of tile t+2
// || barrier || setprio(1) 16-MFMA setprio(0) || barrier}. Counted vmcnt(4) at
// tile end (never drains until the last 2 tiles). This is the fine per-phase
// interleave the R5-R9 coarse variants lacked (m196: the interleave IS the lever).
// Used for MLP1 (M=4096,N=4096,K=1024; uniform 16x16 grid). Requires M,N%256==0,
// K%32==0, nt>=3. Same XOR chunk swizzle algebra as gemm_bt (conflicts=0, R4).
__global__ __launch_bounds__(512, 2) void gemm8_gelu(
    const short* __restrict__ A, const short* __restrict__ Bt,
    const float* __restrict__ bias, short* __restrict__ Cbf, int M, int N, int K)
{
  __shared__ __attribute__((aligned(16))) short As[3][8192];   // 256 x 32
  __shared__ __attribute__((aligned(16))) short Bs[3][8192];
  const int tid = threadIdx.x;
  const int lane = tid & 63, w = tid >> 6;       // 8 waves
  const int l16 = lane & 15, quad = lane >> 4;
  const int wm = w >> 2, wn = w & 3;             // 2M x 4N, wave tile 128x64
  const int gx = (int)gridDim.x, gy = (int)gridDim.y;
  int wg = xcd_swizzle((int)blockIdx.x + gx * (int)blockIdx.y, gx * gy);
  const int bx = wg % gx, by = wg / gx;
  const int bm0 = by << 8, bn0 = bx << 8;
  const int nt = K >> 5;

  // staging: tile = 256 rows x 4 chunks(16B) = 1024 chunks = 512 thr x 2.
  // chunk lin = p*512+tid -> row = p*128 + (tid>>2), chunk col = tid&3.
  // pre-XOR source col with csw=(row>>1)&3=(tid>>3)&3 (same for both p).
  const int csw = (tid >> 3) & 3;
  const int c0 = (tid & 3) ^ csw;
  const int r0 = tid >> 2;                       // 0..127
  const short* ga0 = A  + (long)(bm0 + r0) * K + c0 * 8;
  const short* ga1 = A  + (long)(bm0 + 128 + r0) * K + c0 * 8;
  const short* gb0 = Bt + (long)(bn0 + r0) * K + c0 * 8;
  const short* gb1 = Bt + (long)(bn0 + 128 + r0) * K + c0 * 8;

#define SA(buf, t) do { const long ko_ = (long)(t) * 32;     \
    async16(ga0 + ko_, &As[buf][tid * 8]);                   \
    async16(ga1 + ko_, &As[buf][4096 + tid * 8]); } while (0)
#define SB(buf, t) do { const long ko_ = (long)(t) * 32;     \
    async16(gb0 + ko_, &Bs[buf][tid * 8]);                   \
    async16(gb1 + ko_, &Bs[buf][4096 + tid * 8]); } while (0)

  f32x4 acc[8][4] = {};
  const int qsw = (quad ^ ((l16 >> 1) & 3)) * 8;

  // prologue: stage tiles 0 and 1; wait tile 0 (vmcnt(4): tile-1's 4 in flight)
  SA(0, 0); SB(0, 0); SA(1, 1); SB(1, 1);
  asm volatile("s_waitcnt vmcnt(4)" ::: "memory");
  __builtin_amdgcn_s_barrier();
  __builtin_amdgcn_sched_barrier(0);

  int cur = 0;
  for (int t = 0; t < nt; t++){
    const int nxt = (cur == 2) ? 0 : cur + 1;
    const int stg = (nxt == 2) ? 0 : nxt + 1;    // = (t+2)%3
    short8 af[8], bfr[4];
    // ---- phase A: read i0-3 + all B; stage A-chunks of tile t+2; 16 MFMA ----
#pragma unroll
    for (int i = 0; i < 4; i++)
      af[i] = *(const short8*)&As[cur][(wm * 128 + i * 16 + l16) * 32 + qsw];
#pragma unroll
    for (int j = 0; j < 4; j++)
      bfr[j] = *(const short8*)&Bs[cur][(wn * 64 + j * 16 + l16) * 32 + qsw];
    if (t + 2 < nt) SA(stg, t + 2);
    __builtin_amdgcn_s_barrier();
    __builtin_amdgcn_sched_barrier(0);
    __builtin_amdgcn_s_setprio(1);
#pragma unroll
    for (int i = 0; i < 4; i++)
#pragma unroll
      for (int j = 0; j < 4; j++)
        acc[i][j] = __builtin_amdgcn_mfma_f32_16x16x32_bf16(af[i], bfr[j], acc[i][j], 0, 0, 0);
    __builtin_amdgcn_s_setprio(0);
    __builtin_amdgcn_s_barrier();
    __builtin_amdgcn_sched_barrier(0);
    // ---- phase B: read i4-7; stage B-chunks of tile t+2; 16 MFMA ----
#pragma unroll
    for (int i = 4; i < 8; i++)
      af[i] = *(const short8*)&As[cur][(wm * 128 + i * 16 + l16) * 32 + qsw];
    if (t + 2 < nt) SB(stg, t + 2);
    __builtin_amdgcn_s_barrier();
    __builtin_amdgcn_sched_barrier(0);
    __builtin_amdgcn_s_setprio(1);
#pragma unroll
    for (int i = 4; i < 8; i++)
#pragma unroll
      for (int j = 0; j < 4; j++)
        acc[i][j] = __builtin_amdgcn_mfma_f32_16x16x32_bf16(af[i], bfr[j], acc[i][j], 0, 0, 0);
    __builtin_amdgcn_s_setprio(0);
    // tile-end wait: tile t+1 must be landed for next iteration's reads.
    // t+2<nt: t+2's 4 loads outstanding -> vmcnt(4) retires t+1's (FIFO).
    // t+2>=nt: nothing newer outstanding -> must drain to 0.
    if (t + 1 < nt){
      if (t + 2 < nt) asm volatile("s_waitcnt vmcnt(4)" ::: "memory");
      else            asm volatile("s_waitcnt vmcnt(0)" ::: "memory");
    }
    __builtin_amdgcn_s_barrier();
    __builtin_amdgcn_sched_barrier(0);
    cur = nxt;
  }
#undef SA
#undef SB

  // epilogue: bias + exact gelu -> bf16
#pragma unroll
  for (int i = 0; i < 8; i++){
#pragma unroll
    for (int r = 0; r < 4; r++){
      const int row = bm0 + wm * 128 + i * 16 + quad * 4 + r;
#pragma unroll
      for (int j = 0; j < 4; j++){
        const int col = bn0 + wn * 64 + j * 16 + l16;
        float v = acc[i][j][r] + bias[col];
        v = 0.5f * v * (1.f + erff(v * 0.70710678118654752f));
        Cbf[(long)row * N + col] = f2bf(v);
      }
    }
  }
}

// ---------------- Chunked scans over T (32 chunks x 64), ILP-8 batched ----------------
// p1 also converts V f32 -> bf16 Vh (XNb overlay; XNb dead after proj GEMM)
__global__ __launch_bounds__(256) void scan_p1(float* __restrict__ G, const float* __restrict__ P,
    const float* __restrict__ Vf, short* __restrict__ Vh,
    float* __restrict__ cmax, float* __restrict__ gsum){
  const int tid = blockIdx.x * 256 + threadIdx.x;    // 65536
  const int d = tid & 63, c = (tid >> 6) & 31, bh = tid >> 11;
  const int h = bh & 15, b = bh >> 4;
  const long base = (((long)(b * TSEQ + c * 64)) * NH + h) * 64 + d;
  const long str = NH * 64;
  float mx = -1e30f, gs = 0.f;
  for (int tb = 0; tb < 8; tb++){
    float g[8], p[8], v[8];
#pragma unroll
    for (int j = 0; j < 8; j++){
      const long idx = base + (long)(tb * 8 + j) * str;
      g[j] = G[idx]; p[j] = P[idx]; v[j] = Vf[idx];
    }
#pragma unroll
    for (int j = 0; j < 8; j++){
      const long idx = base + (long)(tb * 8 + j) * str;
      float gj = -softplusf(g[j]);
      G[idx] = gj;
      gs += gj;
      mx = fmaxf(mx, p[j]);
      Vh[idx] = f2bf(v[j]);
    }
  }
  const int chain = bh * 64 + d;
  cmax[chain * 32 + c] = mx;
  gsum[chain * 32 + c] = gs;
}

__global__ void scan_p2(const float* __restrict__ cmax, const float* __restrict__ gsum,
                        float* __restrict__ pmax, float* __restrict__ gpre){
  const int chain = blockIdx.x * 256 + threadIdx.x;  // 2048
  const f32x4* cm4 = (const f32x4*)(cmax + chain * 32);
  const f32x4* gs4 = (const f32x4*)(gsum + chain * 32);
  f32x4* gp4 = (f32x4*)(gpre + chain * 32);
  f32x4 cv[8], gv[8];
#pragma unroll
  for (int i = 0; i < 8; i++){ cv[i] = cm4[i]; gv[i] = gs4[i]; }
  float mx = -1e30f;
#pragma unroll
  for (int i = 0; i < 8; i++)
    mx = fmaxf(mx, fmaxf(fmaxf(cv[i][0], cv[i][1]), fmaxf(cv[i][2], cv[i][3])));
  pmax[chain] = mx;
  float run = 0.f;
#pragma unroll
  for (int i = 0; i < 8; i++){
    f32x4 o;
#pragma unroll
    for (int j = 0; j < 4; j++){ o[j] = run; run += gv[i][j]; }
    gp4[i] = o;
  }
}

// p3 also applies l2norm + RoPE to Q,K (wave lanes == the 64 d-values of one row)
__global__ __launch_bounds__(256) void scan_p3(const float* __restrict__ G, float* __restrict__ P,
    const float* __restrict__ CLKr, float* __restrict__ Q, float* __restrict__ K,
    const float* __restrict__ pmax, const float* __restrict__ gpre, float* __restrict__ psum){
  const int tid = blockIdx.x * 256 + threadIdx.x;
  const int d = tid & 63, c = (tid >> 6) & 31, bh = tid >> 11;
  const int h = bh & 15, b = bh >> 4;
  const int chain = bh * 64 + d;
  const long base = (((long)(b * TSEQ + c * 64)) * NH + h) * 64 + d;
  const long str = NH * 64;
  const float pm = pmax[chain];
  const float freq = expf(-(float)(d >> 1) * 0.28782313662425575f); // ln(1e4)/32
  float sn = sinf((float)(c * 64) * freq);
  float cn = cosf((float)(c * 64) * freq);
  const float sf = sinf(freq), cf = cosf(freq);
  float grun = gpre[chain * 32 + c];
  float ps = 0.f;
  for (int tb = 0; tb < 8; tb++){
    float g[8], p[8], q[8], k[8], ck[8];
#pragma unroll
    for (int j = 0; j < 8; j++){
      const long idx = base + (long)(tb * 8 + j) * str;
      g[j] = G[idx]; p[j] = P[idx]; q[j] = Q[idx]; k[j] = K[idx];
      const int t = c * 64 + tb * 8 + j;
      ck[j] = CLKr[(long)(b * TSEQ + t) * NH + h];
    }
#pragma unroll
    for (int j = 0; j < 8; j++){
      const long idx = base + (long)(tb * 8 + j) * str;
      float clk = softplusf(ck[j]);
      float pe = __expf(p[j] - pm) * clk;
      P[idx] = pe; ps += pe;
      grun += g[j];
      float gc = __expf(fminf(fmaxf(grun, -60.f), 50.f));
      {
        float qq = q[j];
        float s2 = wave_sum(qq * qq);
        qq *= rsqrtf(fmaxf(s2, 1e-24f));       // == q / max(sqrt(s2), 1e-12)
        float pr = __shfl_xor(qq, 1);
        qq = (d & 1) ? fmaf(pr, sn, qq * cn) : fmaf(qq, cn, -pr * sn);
        Q[idx] = qq * gc;
      }
      {
        float kk = k[j];
        float s2 = wave_sum(kk * kk);
        kk *= rsqrtf(fmaxf(s2, 1e-24f));
        float pr = __shfl_xor(kk, 1);
        kk = (d & 1) ? fmaf(pr, sn, kk * cn) : fmaf(kk, cn, -pr * sn);
        K[idx] = kk * __builtin_amdgcn_rcpf(gc + 1e-8f);
      }
      const float ns = fmaf(sn, cf, cn * sf);
      const float nc = fmaf(cn, cf, -sn * sf);
      sn = ns; cn = nc;
    }
  }
  psum[chain * 32 + c] = ps;
}

__global__ void scan_p4(const float* __restrict__ psum, float* __restrict__ ppre){
  const int chain = blockIdx.x * 256 + threadIdx.x;
  const f32x4* ps4 = (const f32x4*)(psum + chain * 32);
  f32x4* pp4 = (f32x4*)(ppre + chain * 32);
  f32x4 pv[8];
#pragma unroll
  for (int i = 0; i < 8; i++) pv[i] = ps4[i];
  float run = 0.f;
#pragma unroll
  for (int i = 0; i < 8; i++){
    f32x4 o;
#pragma unroll
    for (int j = 0; j < 4; j++){ o[j] = run; run += pv[i][j]; }
    pp4[i] = o;
  }
}

// final scan: emits bf16 Qh (pre-scaled by 0.125) and bf16 Kh (V f32 dead by now)
__global__ __launch_bounds__(256) void scan_p5(const float* __restrict__ P, const float* __restrict__ Q,
    const float* __restrict__ K, const float* __restrict__ ppre,
    short* __restrict__ Qh, short* __restrict__ Kh){
  const int tid = blockIdx.x * 256 + threadIdx.x;
  const int d = tid & 63, c = (tid >> 6) & 31, bh = tid >> 11;
  const int h = bh & 15, b = bh >> 4;
  const int chain = bh * 64 + d;
  const long base = (((long)(b * TSEQ + c * 64)) * NH + h) * 64 + d;
  const long str = NH * 64;
  float cs = ppre[chain * 32 + c];
  for (int tb = 0; tb < 8; tb++){
    float p[8], q[8], k[8];
#pragma unroll
    for (int j = 0; j < 8; j++){
      const long idx = base + (long)(tb * 8 + j) * str;
      p[j] = P[idx]; q[j] = Q[idx]; k[j] = K[idx];
    }
#pragma unroll
    for (int j = 0; j < 8; j++){
      const long idx = base + (long)(tb * 8 + j) * str;
      cs += p[j];
      Qh[idx] = f2bf(q[j] * 0.125f * __builtin_amdgcn_rcpf(cs + 1e-8f));
      Kh[idx] = f2bf(k[j] * p[j]);
    }
  }
}

// ------- MFMA flash attention v2: 128-row Q blocks, 8 waves sharing one K/V staging.
// Fixed-m softmax (|s|<=0.125 < 0.25), deferred l, register prefetch, bf16 in/out. -------
__global__ __launch_bounds__(512, 2) void fattn_kernel(const short* __restrict__ Qh,
    const short* __restrict__ Kh, const short* __restrict__ Vh, short* __restrict__ O){
  __shared__ __attribute__((aligned(16))) short Ks[64][72];   // [key][d]
  __shared__ __attribute__((aligned(16))) short Vt[64][68];   // [d][key]
  __shared__ __attribute__((aligned(16))) short Ps[8][16][72];
  const int tid  = threadIdx.x;
  const int lane = tid & 63, w = tid >> 6;            // 8 waves x 16 q-rows
  const int quad = lane >> 4, l16 = lane & 15;
  const int gx = (int)gridDim.x;                      // 16
  int wgs = xcd_swizzle((int)blockIdx.x + gx * (int)blockIdx.y, gx * (int)gridDim.y);
  const int bxs = wgs % gx;
  const int bh = wgs / gx, h = bh & 15, b = bh >> 4;
  const int qt = ((bh >> 1) & 1) ? bxs : (gx - 1 - bxs);
  const int q0  = qt << 7;
  const int qw0 = q0 + w * 16;
  const long strideT = NH * DH;
  const long base_bh = ((long)b * TSEQ * NH + h) * DH;

  const short* qp = Qh + base_bh + (long)(qw0 + l16) * strideT + quad * 8;
  const short8 qa0 = *(const short8*)qp;
  const short8 qa1 = *(const short8*)(qp + 32);

  f32x4 oacc[4] = {{0,0,0,0},{0,0,0,0},{0,0,0,0},{0,0,0,0}};
  float lpart[4] = {0.f,0.f,0.f,0.f};    // per-lane partial row sums (fixed m)

  const int krow = tid >> 3, kcol = (tid & 7) << 3;
  const int vkey = tid & 63, vd0 = w << 3;
  const short* kbase = Kh + base_bh + (long)krow * strideT + kcol;
  const short* vbase = Vh + base_bh + (long)vkey * strideT + vd0;

  short8 kr0 = *(const short8*)kbase;
  short8 vr0 = *(const short8*)vbase;

  const int ntiles = 2 * qt + 2;          // keys 0 .. q0+127 covered
  for (int t = 0; t < ntiles; t++){
    *(short8*)&Ks[krow][kcol] = kr0;
#pragma unroll
    for (int j = 0; j < 8; j++) Vt[vd0 + j][vkey] = vr0[j];
    __syncthreads();
    if (t + 1 < ntiles){
      const long off = (long)(t + 1) * (64 * strideT);
      kr0 = *(const short8*)(kbase + off);
      vr0 = *(const short8*)(vbase + off);
    }
    const int kt0 = t << 6;
    f32x4 c[4] = {{0,0,0,0},{0,0,0,0},{0,0,0,0},{0,0,0,0}};
#pragma unroll
    for (int kg = 0; kg < 4; kg++){
      const short8 b0 = ld8(&Ks[kg * 16 + l16][quad * 8]);
      const short8 b1 = ld8(&Ks[kg * 16 + l16][32 + quad * 8]);
      c[kg] = __builtin_amdgcn_mfma_f32_16x16x32_bf16(qa0, b0, c[kg], 0, 0, 0);
      c[kg] = __builtin_amdgcn_mfma_f32_16x16x32_bf16(qa1, b1, c[kg], 0, 0, 0);
    }
    if (kt0 + 63 > qw0){
#pragma unroll
      for (int kg = 0; kg < 4; kg++)
#pragma unroll
        for (int r = 0; r < 4; r++){
          const int qq = qw0 + quad * 4 + r;
          if (kt0 + kg * 16 + l16 > qq) c[kg][r] = -1e30f;
        }
    }
#pragma unroll
    for (int kg = 0; kg < 4; kg++)
#pragma unroll
      for (int r = 0; r < 4; r++) c[kg][r] = __expf(c[kg][r] - 0.25f);
#pragma unroll
    for (int r = 0; r < 4; r++)
      lpart[r] += (c[0][r] + c[1][r]) + (c[2][r] + c[3][r]);
#pragma unroll
    for (int kg = 0; kg < 4; kg++)
#pragma unroll
      for (int r = 0; r < 4; r++)
        Ps[w][quad * 4 + r][kg * 16 + l16] = f2bf(c[kg][r]);
    const short8 pa0 = ld8(&Ps[w][l16][quad * 8]);
    const short8 pa1 = ld8(&Ps[w][l16][32 + quad * 8]);
#pragma unroll
    for (int f = 0; f < 4; f++){
      const short8 vb0 = ld8(&Vt[f * 16 + l16][quad * 8]);
      const short8 vb1 = ld8(&Vt[f * 16 + l16][32 + quad * 8]);
      oacc[f] = __builtin_amdgcn_mfma_f32_16x16x32_bf16(pa0, vb0, oacc[f], 0, 0, 0);
      oacc[f] = __builtin_amdgcn_mfma_f32_16x16x32_bf16(pa1, vb1, oacc[f], 0, 0, 0);
    }
    __syncthreads();
  }
#pragma unroll
  for (int r = 0; r < 4; r++){
    float l = lpart[r];
#pragma unroll
    for (int o = 1; o <= 8; o <<= 1) l += __shfl_xor(l, o);
    const float inv = 1.f / l;
    const long row = base_bh + (long)(qw0 + quad * 4 + r) * strideT + l16;
#pragma unroll
    for (int f = 0; f < 4; f++) O[row + f * 16] = f2bf(oacc[f][r] * inv);
  }
}

extern "C" void kernel_launch(void* const* d_in, const int* in_sizes, int n_in,
                              void* d_out, int out_size, void* d_ws, size_t ws_size,
                              hipStream_t stream){
  const float* x       = (const float*)d_in[0];
  const float* Wq      = (const float*)d_in[1];
  const float* Wk      = (const float*)d_in[2];
  const float* Wv      = (const float*)d_in[3];
  const float* gate_w  = (const float*)d_in[4];
  const float* gate_b  = (const float*)d_in[5];
  const float* p_w     = (const float*)d_in[6];
  const float* p_b     = (const float*)d_in[7];
  const float* out_w   = (const float*)d_in[8];
  const float* out_b   = (const float*)d_in[9];
  const float* clock_w = (const float*)d_in[10];
  const float* clock_b = (const float*)d_in[11];
  const float* ln1_g   = (const float*)d_in[12];
  const float* ln1_b   = (const float*)d_in[13];
  const float* ln2_g   = (const float*)d_in[14];
  const float* ln2_b   = (const float*)d_in[15];
  const float* mlp_w1  = (const float*)d_in[16];
  const float* mlp_b1  = (const float*)d_in[17];
  const float* mlp_w2  = (const float*)d_in[18];
  const float* mlp_b2  = (const float*)d_in[19];
  float* outp = (float*)d_out;

  // ---- workspace layout (round-8-proven liveness) ----
  float* ws   = (float*)d_ws;
  float* C5   = ws;                     // slots 0..4 f32: Qb,Kb,Vf,Gb,Pb
  float* Qb   = ws;
  float* Kb   = ws + 4194304;
  float* Vf   = ws + 8388608;
  float* Gb   = ws + 12582912;
  float* Pb   = ws + 16777216;          // later X1
  float* CLKr = ws + 20971520;          // slot 5 (row*16 layout)
  float* cmax = CLKr + 65536;
  float* gsum = cmax + 65536;           // psum
  float* gpre = gsum + 65536;           // ppre
  float* pmax = gpre + 65536;
  float* biascat = cmax;                // disjoint lifetime with cmax
  short* sb   = (short*)(ws + 21235712);
  short* XNb  = sb;                     // 4M shorts (LN1 out); Vh overlay after proj
  short* Vh   = sb;                     //   written by scan_p1 (XNb dead by then)
  short* WcT  = sb + 4194304;           // concat [5136][1024] bf16 (q,k,v,gate,p,clock)
  short* OwT  = WcT + 5260288;          // 1M
  short* W1T  = OwT + 1048576;          // 4M [4096][1024]
  short* W2T  = W1T + 4194304;          // 4M [1024][4096]
  // overlays of the V f32 slot [8388608, 12582912) — written in scan_p5, V f32 dead:
  short* Qh  = (short*)(ws + 8388608);            // 8MB
  short* Kh  = (short*)(ws + 8388608 + 2097152);  // 8MB
  // other overlays:
  short* MID = (short*)ws;                        // 16M shorts over Qb+Kb
  short* Ob  = (short*)(ws + 12582912);           // over dead Gb (first 8MB)
  short* Hb  = (short*)(ws + 12582912 + 2097152); // over dead Gb (second 8MB)
  float* X1  = Pb;

  // ---- weight convert+transpose (bf16, [N][K]) ----
  wt6_kernel<<<dim3(32, 32, 6), 256, 0, stream>>>(
      Wq, Wk, Wv, gate_w, p_w, out_w,
      WcT, WcT + 1048576, WcT + 2097152, WcT + 3145728, WcT + 4194304, OwT);
  wt_kernel<<<dim3(1, 32), 256, 0, stream>>>(clock_w, WcT + 5242880, DM, NH);
  wt_kernel<<<dim3(128, 32), 256, 0, stream>>>(mlp_w1, W1T, DM, 4 * DM);
  wt_kernel<<<dim3(32, 128), 256, 0, stream>>>(mlp_w2, W2T, 4 * DM, DM);
  biascat_fill<<<21, 256, 0, stream>>>(gate_b, p_b, clock_b, biascat);

  ln_kernel<<<BT, 256, 0, stream>>>(x, ln1_g, ln1_b, XNb);

  // fused Q/K/V/gate/p/clock projection: N = 5136, scatter epilogue (128^2 tiles)
  gemm_bt<5><<<dim3(41, BT / 128), 256, 0, stream>>>(
      XNb, WcT, biascat, nullptr, nullptr, nullptr, C5, nullptr, BT, 5136, DM);

  scan_p1<<<256, 256, 0, stream>>>(Gb, Pb, Vf, Vh, cmax, gsum);
  scan_p2<<<8, 256, 0, stream>>>(cmax, gsum, pmax, gpre);
  scan_p3<<<256, 256, 0, stream>>>(Gb, Pb, CLKr, Qb, Kb, pmax, gpre, gsum);
  scan_p4<<<8, 256, 0, stream>>>(gsum, gpre);
  scan_p5<<<256, 256, 0, stream>>>(Pb, Qb, Kb, gpre, Qh, Kh);

  // flash attention: 128-row q blocks, 8 waves (512 blocks, 2/CU)
  fattn_kernel<<<dim3(TSEQ / 128, 2 * NH), 512, 0, stream>>>(Qh, Kh, Vh, Ob);

  // out-proj: X1 = attn@out_w + out_b + x, fused init outp = X1 + mlp_b2 (128^2 tiles)
  gemm_bt<4><<<dim3(DM / 128, BT / 128), 256, 0, stream>>>(
      Ob, OwT, out_b, x, mlp_b2, outp, X1, nullptr, BT, DM, DM);
  ln_kernel<<<BT, 256, 0, stream>>>(X1, ln2_g, ln2_b, Hb);
  // MLP1: 8-phase fine-interleave experiment (256^2, BK=32, 16x16 grid)
  gemm8_gelu<<<dim3(4 * DM / 256, BT / 256), 512, 0, stream>>>(
      Hb, W1T, mlp_b1, MID, BT, 4 * DM, DM);
  // MLP2: split-K=2 (512 wg = 2/CU, half the atomic traffic of split-K=4)
  gemm_bt<6><<<dim3(DM / 128, BT / 128, 2), 256, 0, stream>>>(
      MID, W2T, nullptr, nullptr, nullptr, nullptr, outp, nullptr, BT, DM, 4 * DM);
}